// Round 13
// baseline (6934.620 us; speedup 1.0000x reference)
//
#include <hip/hip_runtime.h>
#include <hip/hip_bf16.h>
#include <cstdint>

#define B_  512
#define D_  1024
#define E_  4
#define L_  2
#define FF_ 4096
#define ND_ 3
#define BT_ 1536   // ND_*B_
#define STEPS_ 5
#define H_ 8
#define PROWS 3584         // max sum of pad128(3*cnt_e) over experts
#define TROWS (PROWS * STEPS_)

typedef __attribute__((ext_vector_type(8))) __bf16 bf16x8;
typedef __attribute__((ext_vector_type(8))) unsigned short u16x8;
typedef __attribute__((ext_vector_type(4))) float f32x4;

static __device__ __forceinline__ float gelu_f(float x) {
    return 0.5f * x * (1.0f + erff(x * 0.70710678118654752f));
}

static __device__ __forceinline__ unsigned short f2bf(float x) {
    unsigned u = __builtin_bit_cast(unsigned, x);
    u = (u + 0x7fff + ((u >> 16) & 1)) >> 16;   // RNE
    return (unsigned short)u;
}

static __device__ __forceinline__ float bf2f(unsigned short us) {
    unsigned v = (unsigned)us << 16;
    return __builtin_bit_cast(float, v);
}

static __device__ __forceinline__ void gload16(const void* g, void* l) {
    __builtin_amdgcn_global_load_lds(
        (const __attribute__((address_space(1))) unsigned int*)g,
        (__attribute__((address_space(3))) unsigned int*)l, 16, 0, 0);
}

static __device__ __forceinline__ int pad128(int x) { return (x + 127) & ~127; }

// =====================================================================
// Variant A (fallback): in-kernel W f32->bf16 conversion (round-12 kernel).
// =====================================================================
template<int ACT, int OUTBF>
__global__ __launch_bounds__(512) void gemm_wf32(
    const unsigned short* __restrict__ A,
    const float* __restrict__ Wb, long wstride, int LDA,
    const float* __restrict__ biasb, long bstride,
    const float* __restrict__ R, long Rld, void* __restrict__ Cout, int N, int K,
    const int* __restrict__ roff, int T)
{
    const long row0 = (long)blockIdx.y * 128;
    if ((int)row0 >= roff[4] * T) return;
    int e = 0;
    while (e < 3 && (int)row0 >= roff[e + 1] * T) ++e;
    const float* W = Wb + (long)e * wstride;
    const float* bias = biasb ? (biasb + (long)e * bstride) : nullptr;

    __shared__ __align__(16) unsigned short As[2 * 128 * 32];
    __shared__ __align__(16) unsigned short Bs[2 * 128 * 32];
    const int t = threadIdx.x;
    const int lane = t & 63;
    const int wid = t >> 6;
    const int wr = wid >> 1;
    const int wc = wid & 1;
    const long col0 = (long)blockIdx.x * 128;
    const int l15 = lane & 15, l4 = lane >> 4;

    f32x4 acc[2][4] = {};

    const unsigned short* Ag = A + (row0 + (t >> 2)) * (long)K + (t & 3) * 8;
    char* AdBase = (char*)As + t * 16;
    const float* Wg = W + (long)(col0 + (t >> 2)) * LDA + (t & 3) * 8;

    const int K32 = K >> 5;
    float4 w0, w1;

    gload16(Ag, AdBase);
    w0 = *(const float4*)(Wg);
    w1 = *(const float4*)(Wg + 4);
    {
        u16x8 p = {f2bf(w0.x), f2bf(w0.y), f2bf(w0.z), f2bf(w0.w),
                   f2bf(w1.x), f2bf(w1.y), f2bf(w1.z), f2bf(w1.w)};
        *(u16x8*)((char*)Bs + t * 16) = p;
    }
    if (K32 > 1) {
        w0 = *(const float4*)(Wg + 32);
        w1 = *(const float4*)(Wg + 36);
    }
    __syncthreads();

    for (int j = 0; j < K32; ++j) {
        const int cur = j & 1;
        const int nxt = cur ^ 1;
        if (j + 1 < K32) {
            gload16(Ag + ((j + 1) << 5), AdBase + nxt * 8192);
            u16x8 p = {f2bf(w0.x), f2bf(w0.y), f2bf(w0.z), f2bf(w0.w),
                       f2bf(w1.x), f2bf(w1.y), f2bf(w1.z), f2bf(w1.w)};
            *(u16x8*)((char*)Bs + nxt * 8192 + t * 16) = p;
        }
        if (j + 2 < K32) {
            const int k2 = (j + 2) << 5;
            w0 = *(const float4*)(Wg + k2);
            w1 = *(const float4*)(Wg + k2 + 4);
        }
        bf16x8 af[2], bf[4];
        #pragma unroll
        for (int m = 0; m < 2; ++m)
            af[m] = *(const bf16x8*)((const char*)As + cur * 8192 + (wr * 32 + m * 16 + l15) * 64 + l4 * 16);
        #pragma unroll
        for (int n = 0; n < 4; ++n)
            bf[n] = *(const bf16x8*)((const char*)Bs + cur * 8192 + (wc * 64 + n * 16 + l15) * 64 + l4 * 16);
        __builtin_amdgcn_s_setprio(1);
        #pragma unroll
        for (int m = 0; m < 2; ++m)
            #pragma unroll
            for (int n = 0; n < 4; ++n)
                acc[m][n] = __builtin_amdgcn_mfma_f32_16x16x32_bf16(af[m], bf[n], acc[m][n], 0, 0, 0);
        __builtin_amdgcn_s_setprio(0);
        __syncthreads();
    }

    #pragma unroll
    for (int n = 0; n < 4; ++n) {
        const long col = col0 + wc * 64 + n * 16 + l15;
        const float bn = bias ? bias[col] : 0.0f;
        #pragma unroll
        for (int m = 0; m < 2; ++m) {
            const long rbase = row0 + wr * 32 + m * 16 + l4 * 4;
            #pragma unroll
            for (int r = 0; r < 4; ++r) {
                float o = acc[m][n][r] + bn;
                if (ACT) o = gelu_f(o);
                const long coff = (rbase + r) * (long)N + col;
                if (R) o += R[(rbase + r) * Rld + col];
                if (OUTBF) ((unsigned short*)Cout)[coff] = f2bf(o);
                else       ((float*)Cout)[coff] = o;
            }
        }
    }
}

// =====================================================================
// Variant B (mirror): both operands bf16 via pure global_load_lds DMA.
// Per K-step: 2 gloads + 8 MFMA + 1 barrier — no VALU staging at all.
// W values are the same RNE-converted bf16 -> output bit-identical to A.
// =====================================================================
template<int ACT, int OUTBF>
__global__ __launch_bounds__(512) void gemm_bb(
    const unsigned short* __restrict__ A,
    const unsigned short* __restrict__ Wb, long wstride, int LDA,
    const float* __restrict__ biasb, long bstride,
    const float* __restrict__ R, long Rld, void* __restrict__ Cout, int N, int K,
    const int* __restrict__ roff, int T)
{
    const long row0 = (long)blockIdx.y * 128;
    if ((int)row0 >= roff[4] * T) return;
    int e = 0;
    while (e < 3 && (int)row0 >= roff[e + 1] * T) ++e;
    const unsigned short* W = Wb + (long)e * wstride;
    const float* bias = biasb ? (biasb + (long)e * bstride) : nullptr;

    __shared__ __align__(16) unsigned short As[2 * 128 * 32];
    __shared__ __align__(16) unsigned short Bs[2 * 128 * 32];
    const int t = threadIdx.x;
    const int lane = t & 63;
    const int wid = t >> 6;
    const int wr = wid >> 1;
    const int wc = wid & 1;
    const long col0 = (long)blockIdx.x * 128;
    const int l15 = lane & 15, l4 = lane >> 4;

    f32x4 acc[2][4] = {};

    const unsigned short* Ag = A + (row0 + (t >> 2)) * (long)K + (t & 3) * 8;
    const unsigned short* Wg = W + (long)(col0 + (t >> 2)) * LDA + (t & 3) * 8;
    char* AdBase = (char*)As + t * 16;
    char* BdBase = (char*)Bs + t * 16;

    const int K32 = K >> 5;

    gload16(Ag, AdBase);
    gload16(Wg, BdBase);
    __syncthreads();

    for (int j = 0; j < K32; ++j) {
        const int cur = j & 1;
        const int nxt = cur ^ 1;
        if (j + 1 < K32) {
            const int k1 = (j + 1) << 5;
            gload16(Ag + k1, AdBase + nxt * 8192);
            gload16(Wg + k1, BdBase + nxt * 8192);
        }
        bf16x8 af[2], bf[4];
        #pragma unroll
        for (int m = 0; m < 2; ++m)
            af[m] = *(const bf16x8*)((const char*)As + cur * 8192 + (wr * 32 + m * 16 + l15) * 64 + l4 * 16);
        #pragma unroll
        for (int n = 0; n < 4; ++n)
            bf[n] = *(const bf16x8*)((const char*)Bs + cur * 8192 + (wc * 64 + n * 16 + l15) * 64 + l4 * 16);
        __builtin_amdgcn_s_setprio(1);
        #pragma unroll
        for (int m = 0; m < 2; ++m)
            #pragma unroll
            for (int n = 0; n < 4; ++n)
                acc[m][n] = __builtin_amdgcn_mfma_f32_16x16x32_bf16(af[m], bf[n], acc[m][n], 0, 0, 0);
        __builtin_amdgcn_s_setprio(0);
        __syncthreads();
    }

    #pragma unroll
    for (int n = 0; n < 4; ++n) {
        const long col = col0 + wc * 64 + n * 16 + l15;
        const float bn = bias ? bias[col] : 0.0f;
        #pragma unroll
        for (int m = 0; m < 2; ++m) {
            const long rbase = row0 + wr * 32 + m * 16 + l4 * 4;
            #pragma unroll
            for (int r = 0; r < 4; ++r) {
                float o = acc[m][n][r] + bn;
                if (ACT) o = gelu_f(o);
                const long coff = (rbase + r) * (long)N + col;
                if (R) o += R[(rbase + r) * Rld + col];
                if (OUTBF) ((unsigned short*)Cout)[coff] = f2bf(o);
                else       ((float*)Cout)[coff] = o;
            }
        }
    }
}

// ---------------- f32 GEMM (gating only — bit-stable expert pick) ----------------
__global__ __launch_bounds__(256) void gemm_f32(
    const float* __restrict__ A, const float* __restrict__ W,
    const float* __restrict__ bias, const float* __restrict__ R,
    float* __restrict__ C, int M, int N, int K, int act)
{
    __shared__ float As[16][68];
    __shared__ float Bs[16][68];
    const int tid = threadIdx.x;
    const int tx = tid & 15;
    const int ty = tid >> 4;
    const long row0 = (long)blockIdx.y * 64;
    const long col0 = (long)blockIdx.x * 64;
    const int lr = tid >> 2;
    const int lq = (tid & 3) << 2;
    const float* Ap = A + (row0 + lr) * (long)K + lq;
    const float* Wp = W + (col0 + lr) * (long)K + lq;
    float acc[4][4] = {};
    for (int k0 = 0; k0 < K; k0 += 16) {
        const float4 av = *(const float4*)(Ap + k0);
        const float4 wv = *(const float4*)(Wp + k0);
        __syncthreads();
        As[lq + 0][lr] = av.x; As[lq + 1][lr] = av.y;
        As[lq + 2][lr] = av.z; As[lq + 3][lr] = av.w;
        Bs[lq + 0][lr] = wv.x; Bs[lq + 1][lr] = wv.y;
        Bs[lq + 2][lr] = wv.z; Bs[lq + 3][lr] = wv.w;
        __syncthreads();
        #pragma unroll
        for (int kk = 0; kk < 16; ++kk) {
            const float4 a4 = *(const float4*)&As[kk][ty << 2];
            const float4 b4 = *(const float4*)&Bs[kk][tx << 2];
            const float aa[4] = {a4.x, a4.y, a4.z, a4.w};
            const float bb[4] = {b4.x, b4.y, b4.z, b4.w};
            #pragma unroll
            for (int i = 0; i < 4; ++i)
                #pragma unroll
                for (int j = 0; j < 4; ++j)
                    acc[i][j] = fmaf(aa[i], bb[j], acc[i][j]);
        }
    }
    const float4 bv = *(const float4*)(bias + col0 + (tx << 2));
    const float bb[4] = {bv.x, bv.y, bv.z, bv.w};
    #pragma unroll
    for (int i = 0; i < 4; ++i) {
        const long row = row0 + (ty << 2) + i;
        const long off = row * (long)N + col0 + (tx << 2);
        float o[4];
        #pragma unroll
        for (int j = 0; j < 4; ++j) {
            o[j] = acc[i][j] + bb[j];
            if (act) o[j] = gelu_f(o[j]);
        }
        if (R) {
            const float4 rv = *(const float4*)(R + off);
            o[0] += rv.x; o[1] += rv.y; o[2] += rv.z; o[3] += rv.w;
        }
        *(float4*)(C + off) = make_float4(o[0], o[1], o[2], o[3]);
    }
}

// ---------------- LayerNorm (plain, gating, fused GELU) ----------------
__global__ __launch_bounds__(256) void ln_gate(
    const float* __restrict__ X,
    const float* __restrict__ gamma, const float* __restrict__ beta,
    float* __restrict__ Y)
{
    const long r = blockIdx.x;
    const int tid = threadIdx.x;
    __shared__ float red[8];
    const float4 v = *(const float4*)(X + (r << 10) + (tid << 2));
    float s = v.x + v.y + v.z + v.w;
    #pragma unroll
    for (int off = 32; off; off >>= 1) s += __shfl_xor(s, off);
    if ((tid & 63) == 0) red[tid >> 6] = s;
    __syncthreads();
    const float mean = (red[0] + red[1] + red[2] + red[3]) * (1.0f / 1024.0f);
    const float dx = v.x - mean, dy = v.y - mean, dz = v.z - mean, dw = v.w - mean;
    float s2 = dx * dx + dy * dy + dz * dz + dw * dw;
    #pragma unroll
    for (int off = 32; off; off >>= 1) s2 += __shfl_xor(s2, off);
    if ((tid & 63) == 0) red[4 + (tid >> 6)] = s2;
    __syncthreads();
    const float var = (red[4] + red[5] + red[6] + red[7]) * (1.0f / 1024.0f);
    const float inv = rsqrtf(var + 1e-5f);
    const float4 g = *(const float4*)(gamma + (tid << 2));
    const float4 b = *(const float4*)(beta + (tid << 2));
    float o0 = gelu_f(dx * inv * g.x + b.x);
    float o1 = gelu_f(dy * inv * g.y + b.y);
    float o2 = gelu_f(dz * inv * g.z + b.z);
    float o3 = gelu_f(dw * inv * g.w + b.w);
    *(float4*)(Y + (r << 10) + (tid << 2)) = make_float4(o0, o1, o2, o3);
}

// ---------------- LayerNorm, expert-batched gamma/beta, bf16 out ----------------
__global__ __launch_bounds__(256) void ln_bt(
    const float* __restrict__ X, long xstride,
    const float* __restrict__ gammaB, const float* __restrict__ betaB, long gstride,
    unsigned short* __restrict__ Y, const int* __restrict__ roff, int T)
{
    const long r = blockIdx.x;
    if ((int)r >= roff[4] * T) return;
    int e = 0;
    while (e < 3 && (int)r >= roff[e + 1] * T) ++e;
    const float* gamma = gammaB + (long)e * gstride;
    const float* beta  = betaB  + (long)e * gstride;

    const int tid = threadIdx.x;
    __shared__ float red[8];
    const float4 v = *(const float4*)(X + r * xstride + (tid << 2));
    float s = v.x + v.y + v.z + v.w;
    #pragma unroll
    for (int off = 32; off; off >>= 1) s += __shfl_xor(s, off);
    if ((tid & 63) == 0) red[tid >> 6] = s;
    __syncthreads();
    const float mean = (red[0] + red[1] + red[2] + red[3]) * (1.0f / 1024.0f);
    const float dx = v.x - mean, dy = v.y - mean, dz = v.z - mean, dw = v.w - mean;
    float s2 = dx * dx + dy * dy + dz * dz + dw * dw;
    #pragma unroll
    for (int off = 32; off; off >>= 1) s2 += __shfl_xor(s2, off);
    if ((tid & 63) == 0) red[4 + (tid >> 6)] = s2;
    __syncthreads();
    const float var = (red[4] + red[5] + red[6] + red[7]) * (1.0f / 1024.0f);
    const float inv = rsqrtf(var + 1e-5f);
    const float4 g = *(const float4*)(gamma + (tid << 2));
    const float4 b = *(const float4*)(beta + (tid << 2));
    const float o0 = dx * inv * g.x + b.x;
    const float o1 = dy * inv * g.y + b.y;
    const float o2 = dz * inv * g.z + b.z;
    const float o3 = dw * inv * g.w + b.w;
    ushort4 o = make_ushort4(f2bf(o0), f2bf(o1), f2bf(o2), f2bf(o3));
    *(ushort4*)(Y + (r << 10) + (tid << 2)) = o;
}

// ---------------- FUSED: st = seq+pos; write st; LayerNorm(st) -> bf16 Y ----------------
__global__ __launch_bounds__(256) void ln_st_bt(
    const float* __restrict__ seq, const float* __restrict__ posb,
    float* __restrict__ st,
    const float* __restrict__ gammaB, const float* __restrict__ betaB, long gstride,
    unsigned short* __restrict__ Y, const int* __restrict__ roff, int T)
{
    const int r = blockIdx.x;           // trow in [0, PROWS*T)
    const int prow = r / T;
    if (prow >= roff[4]) return;
    int e = 0;
    while (e < 3 && prow >= roff[e + 1]) ++e;
    const int tau = r - prow * T;
    const float* gamma = gammaB + (long)e * gstride;
    const float* beta  = betaB  + (long)e * gstride;

    const int tid = threadIdx.x;
    const int d4 = tid << 2;
    __shared__ float red[8];
    const float4 sv = *(const float4*)(seq + (((long)tau * PROWS + prow) << 10) + d4);
    const float4 pv = *(const float4*)(posb + (((long)e * 10 + tau) << 10) + d4);
    const float4 v = make_float4(sv.x + pv.x, sv.y + pv.y, sv.z + pv.z, sv.w + pv.w);
    *(float4*)(st + ((long)r << 10) + d4) = v;

    float s = v.x + v.y + v.z + v.w;
    #pragma unroll
    for (int off = 32; off; off >>= 1) s += __shfl_xor(s, off);
    if ((tid & 63) == 0) red[tid >> 6] = s;
    __syncthreads();
    const float mean = (red[0] + red[1] + red[2] + red[3]) * (1.0f / 1024.0f);
    const float dx = v.x - mean, dy = v.y - mean, dz = v.z - mean, dw = v.w - mean;
    float s2 = dx * dx + dy * dy + dz * dz + dw * dw;
    #pragma unroll
    for (int off = 32; off; off >>= 1) s2 += __shfl_xor(s2, off);
    if ((tid & 63) == 0) red[4 + (tid >> 6)] = s2;
    __syncthreads();
    const float var = (red[4] + red[5] + red[6] + red[7]) * (1.0f / 1024.0f);
    const float inv = rsqrtf(var + 1e-5f);
    const float4 g = *(const float4*)(gamma + d4);
    const float4 b = *(const float4*)(beta + d4);
    const float o0 = dx * inv * g.x + b.x;
    const float o1 = dy * inv * g.y + b.y;
    const float o2 = dz * inv * g.z + b.z;
    const float o3 = dw * inv * g.w + b.w;
    ushort4 o = make_ushort4(f2bf(o0), f2bf(o1), f2bf(o2), f2bf(o3));
    *(ushort4*)(Y + ((long)r << 10) + d4) = o;
}

// ---------------- attention (all queries): bf16 qkv in, bf16 out ----------------
template<int TT>
__global__ __launch_bounds__(256) void attn_bt(
    const unsigned short* __restrict__ qkv, unsigned short* __restrict__ o,
    const int* __restrict__ roff)
{
    const int item = (int)(((long)blockIdx.x * 256 + threadIdx.x) >> 6);
    const int lane = threadIdx.x & 63;
    const int tq = item % TT;
    const int h  = (item / TT) & 7;
    const int i  = item / (TT * 8);
    if (i >= roff[4]) return;
    const unsigned short* base = qkv + (long)i * TT * 3072;
    const unsigned short* q = base + (long)tq * 3072 + h * 128;
    const float q0 = bf2f(q[lane]), q1 = bf2f(q[lane + 64]);
    float s[TT];
    const float scale = 0.088388347648318447f;  // 1/sqrt(128)
    #pragma unroll
    for (int tk = 0; tk < TT; ++tk) {
        const unsigned short* k = base + (long)tk * 3072 + 1024 + h * 128;
        float p = q0 * bf2f(k[lane]) + q1 * bf2f(k[lane + 64]);
        #pragma unroll
        for (int off = 32; off; off >>= 1) p += __shfl_xor(p, off);
        s[tk] = p * scale;
    }
    float m = s[0];
    #pragma unroll
    for (int tk = 1; tk < TT; ++tk) m = fmaxf(m, s[tk]);
    float den = 0.f;
    #pragma unroll
    for (int tk = 0; tk < TT; ++tk) { s[tk] = expf(s[tk] - m); den += s[tk]; }
    float o0 = 0.f, o1 = 0.f;
    #pragma unroll
    for (int tk = 0; tk < TT; ++tk) {
        const unsigned short* v = base + (long)tk * 3072 + 2048 + h * 128;
        o0 += s[tk] * bf2f(v[lane]); o1 += s[tk] * bf2f(v[lane + 64]);
    }
    const float id = 1.0f / den;
    unsigned short* op = o + ((long)i * TT + tq) * 1024 + h * 128;
    op[lane] = f2bf(o0 * id); op[lane + 64] = f2bf(o1 * id);
}

// ---------------- attention (LAST query only): compact out (PROWS x 1024) ----------------
template<int TT>
__global__ __launch_bounds__(256) void attn_last(
    const unsigned short* __restrict__ qkv, unsigned short* __restrict__ o,
    const int* __restrict__ roff)
{
    const int item = (int)(((long)blockIdx.x * 256 + threadIdx.x) >> 6);
    const int lane = threadIdx.x & 63;
    const int h  = item & 7;
    const int i  = item >> 3;
    if (i >= roff[4]) return;
    const unsigned short* base = qkv + (long)i * TT * 3072;
    const unsigned short* q = base + (long)(TT - 1) * 3072 + h * 128;
    const float q0 = bf2f(q[lane]), q1 = bf2f(q[lane + 64]);
    float s[TT];
    const float scale = 0.088388347648318447f;
    #pragma unroll
    for (int tk = 0; tk < TT; ++tk) {
        const unsigned short* k = base + (long)tk * 3072 + 1024 + h * 128;
        float p = q0 * bf2f(k[lane]) + q1 * bf2f(k[lane + 64]);
        #pragma unroll
        for (int off = 32; off; off >>= 1) p += __shfl_xor(p, off);
        s[tk] = p * scale;
    }
    float m = s[0];
    #pragma unroll
    for (int tk = 1; tk < TT; ++tk) m = fmaxf(m, s[tk]);
    float den = 0.f;
    #pragma unroll
    for (int tk = 0; tk < TT; ++tk) { s[tk] = expf(s[tk] - m); den += s[tk]; }
    float o0 = 0.f, o1 = 0.f;
    #pragma unroll
    for (int tk = 0; tk < TT; ++tk) {
        const unsigned short* v = base + (long)tk * 3072 + 2048 + h * 128;
        o0 += s[tk] * bf2f(v[lane]); o1 += s[tk] * bf2f(v[lane + 64]);
    }
    const float id = 1.0f / den;
    unsigned short* op = o + (long)i * 1024 + h * 128;
    op[lane] = f2bf(o0 * id); op[lane + 64] = f2bf(o1 * id);
}

// ---------------- gating ----------------
__global__ __launch_bounds__(256) void gate_kernel(
    const float* __restrict__ g, const float* __restrict__ gw2,
    const float* __restrict__ gb2, float* __restrict__ wout)
{
    const int b = (int)(((long)blockIdx.x * 256 + threadIdx.x) >> 6);
    const int lane = threadIdx.x & 63;
    float acc[E_] = {};
    const float* row = g + (long)b * 1024;
    for (int d = lane; d < 1024; d += 64) {
        const float x = row[d];
        #pragma unroll
        for (int j = 0; j < E_; ++j) acc[j] += x * gw2[j * 1024 + d];
    }
    #pragma unroll
    for (int j = 0; j < E_; ++j) {
        #pragma unroll
        for (int off = 32; off; off >>= 1) acc[j] += __shfl_xor(acc[j], off);
        acc[j] += gb2[j];
    }
    int i0 = 0; float v0 = acc[0];
    #pragma unroll
    for (int j = 1; j < E_; ++j) if (acc[j] > v0) { v0 = acc[j]; i0 = j; }
    int i1 = -1; float v1 = -1e30f;
    #pragma unroll
    for (int j = 0; j < E_; ++j) if (j != i0 && acc[j] > v1) { v1 = acc[j]; i1 = j; }
    const float p1 = expf(v1 - v0);
    const float den = 1.0f + p1;
    const float g0 = 1.0f / den, g1 = p1 / den;
    if (lane < E_) wout[b * E_ + lane] = (lane == i0) ? g0 : (lane == i1) ? g1 : 0.0f;
}

// single block: per-expert compact lists + packed-row offsets
__global__ __launch_bounds__(64) void build_idx2_kernel(
    const float* __restrict__ wbuf, int* __restrict__ idx,
    int* __restrict__ cnt3, int* __restrict__ roff)
{
    const int lane = threadIdx.x;
    int pads[E_];
    for (int e = 0; e < E_; ++e) {
        int* my = idx + e * BT_;
        int base = 0;
        for (int chunk = 0; chunk < 8; ++chunk) {
            const int b = chunk * 64 + lane;
            const bool sel = wbuf[b * E_ + e] > 0.0f;
            const unsigned long long mask = __ballot(sel);
            const int pos = base + (int)__popcll(mask & ((1ull << lane) - 1ull));
            if (sel) {
                my[3 * pos + 0] = b;
                my[3 * pos + 1] = 512 + b;
                my[3 * pos + 2] = 1024 + b;
            }
            base += (int)__popcll(mask);
        }
        if (lane == 0) cnt3[e] = 3 * base;
        pads[e] = pad128(3 * base);
    }
    if (lane == 0) {
        roff[0] = 0;
        for (int e = 0; e < E_; ++e) roff[e + 1] = roff[e] + pads[e];
    }
}

// packed seq0: prow -> (e, j); gather or zero
__global__ __launch_bounds__(256) void seq0_bt(
    const float* __restrict__ w, const float* __restrict__ a,
    const float* __restrict__ rr, const float* __restrict__ doff,
    const int* __restrict__ idx, const int* __restrict__ cnt3,
    const int* __restrict__ roff, float* __restrict__ seq0)
{
    const int prow = blockIdx.x;
    if (prow >= roff[4]) return;
    int e = 0;
    while (e < 3 && prow >= roff[e + 1]) ++e;
    const int j = prow - roff[e];
    const int d4 = threadIdx.x << 2;
    float4 res = make_float4(0.f, 0.f, 0.f, 0.f);
    if (j < cnt3[e]) {
        const int v = idx[e * BT_ + j];
        const int n = v >> 9, b = v & 511;
        const float4 x = *(const float4*)(w + ((long)b << 10) + d4);
        const float4 y = *(const float4*)(a + ((long)b << 10) + d4);
        const float4 z = *(const float4*)(rr + ((long)b << 10) + d4);
        const float4 o0 = *(const float4*)(doff + ((long)(n * 3 + 0) << 10) + d4);
        const float4 o1 = *(const float4*)(doff + ((long)(n * 3 + 1) << 10) + d4);
        const float4 o2 = *(const float4*)(doff + ((long)(n * 3 + 2) << 10) + d4);
        const float c = 1.0f / 3.0f;
        res = make_float4(
            (x.x + y.x + z.x + o0.x + o1.x + o2.x) * c,
            (x.y + y.y + z.y + o0.y + o1.y + o2.y) * c,
            (x.z + y.z + z.z + o0.z + o1.z + o2.z) * c,
            (x.w + y.w + z.w + o0.w + o1.w + o2.w) * c);
    }
    *(float4*)(seq0 + ((long)prow << 10) + d4) = res;
}

// seq[t+1][prow] = mean over 3 chunks of O (f32, stride 3072)
__global__ __launch_bounds__(256) void mean3_bt(
    const float* __restrict__ O, float* __restrict__ dst,
    const int* __restrict__ roff)
{
    const int r = blockIdx.x;
    if (r >= roff[4]) return;
    const int d4 = threadIdx.x << 2;
    const float* p = O + (long)r * 3072 + d4;
    const float4 x = *(const float4*)p;
    const float4 y = *(const float4*)(p + 1024);
    const float4 z = *(const float4*)(p + 2048);
    const float c = 1.0f / 3.0f;
    *(float4*)(dst + ((long)r << 10) + d4) = make_float4(
        (x.x + y.x + z.x) * c, (x.y + y.y + z.y) * c,
        (x.z + y.z + z.z) * c, (x.w + y.w + z.w) * c);
}

// out[n,s,:,b,:] += w[b][e] * O[roff[e]+r, :]   (one expert per launch)
__global__ __launch_bounds__(256) void scatter_bt(
    const float* __restrict__ O, const float* __restrict__ wbuf,
    const int* __restrict__ idx, const int* __restrict__ cnt3,
    const int* __restrict__ roff, float* __restrict__ out, int e, int s)
{
    const int r = blockIdx.x;
    if (r >= cnt3[e]) return;
    const int prow = roff[e] + r;
    const int v = idx[e * BT_ + r];
    const int n = v >> 9, b = v & 511;
    const float wgt = wbuf[b * E_ + e];
    const int d4 = threadIdx.x << 2;
    const float* orow = O + (long)prow * 3072;
    #pragma unroll
    for (int c = 0; c < 3; ++c) {
        const float4 t = *(const float4*)(orow + c * 1024 + d4);
        float* op = out + (((long)((n * STEPS_ + s) * 3 + c) * B_ + b) << 10) + d4;
        float4 o = *(const float4*)op;
        o.x += wgt * t.x; o.y += wgt * t.y; o.z += wgt * t.z; o.w += wgt * t.w;
        *(float4*)op = o;
    }
}

__global__ __launch_bounds__(256) void build_flat_kernel(
    const float* __restrict__ w, const float* __restrict__ a,
    const float* __restrict__ r, float* __restrict__ flat)
{
    const long e4 = ((long)blockIdx.x * 256 + threadIdx.x) << 2;
    const int b = (int)(e4 / 3072);
    const int cd = (int)(e4 % 3072);
    const int c = cd >> 10, d = cd & 1023;
    const float* src = (c == 0) ? w : (c == 1) ? a : r;
    *(float4*)(flat + e4) = *(const float4*)(src + ((long)b << 10) + d);
}

__global__ __launch_bounds__(256) void zero_kernel(float* __restrict__ p, long n4)
{
    const long stride = (long)gridDim.x * 256;
    for (long i = (long)blockIdx.x * 256 + threadIdx.x; i < n4; i += stride)
        *(float4*)(p + i * 4) = make_float4(0.f, 0.f, 0.f, 0.f);
}

// f32 -> bf16 (RNE), vectorized; n4 = count/4
__global__ __launch_bounds__(256) void cvt_bf16_kernel(
    const float* __restrict__ src, unsigned short* __restrict__ dst, long n4)
{
    const long stride = (long)gridDim.x * 256;
    for (long i = (long)blockIdx.x * 256 + threadIdx.x; i < n4; i += stride) {
        const float4 v = *(const float4*)(src + i * 4);
        ushort4 o = make_ushort4(f2bf(v.x), f2bf(v.y), f2bf(v.z), f2bf(v.w));
        *(ushort4*)(dst + i * 4) = o;
    }
}

// =====================================================================
// Host-side GEMM dispatch: mirror (bf16 W, pure DMA) vs fallback (f32 W).
// =====================================================================
template<int ACT, int OUTBF>
static inline void G(bool mir, dim3 grid, hipStream_t s,
                     const unsigned short* A,
                     const float* Wf, const unsigned short* Wm, long wstride, int LDA,
                     const float* bias, long bstride,
                     const float* R, long Rld, void* C, int N, int K,
                     const int* roff, int T)
{
    if (mir) gemm_bb<ACT, OUTBF><<<grid, 512, 0, s>>>(A, Wm, wstride, LDA, bias, bstride, R, Rld, C, N, K, roff, T);
    else     gemm_wf32<ACT, OUTBF><<<grid, 512, 0, s>>>(A, Wf, wstride, LDA, bias, bstride, R, Rld, C, N, K, roff, T);
}

// =====================================================================
//                          HOST LAUNCH
// =====================================================================

extern "C" void kernel_launch(void* const* d_in, const int* in_sizes, int n_in,
                              void* d_out, int out_size, void* d_ws, size_t ws_size,
                              hipStream_t stream)
{
    const float* iw   = (const float*)d_in[0];
    const float* ia   = (const float*)d_in[1];
    const float* ir   = (const float*)d_in[2];
    const float* doff = (const float*)d_in[3];
    const float* gw1  = (const float*)d_in[4];
    const float* gb1  = (const float*)d_in[5];
    const float* glnw = (const float*)d_in[6];
    const float* glnb = (const float*)d_in[7];
    const float* gw2  = (const float*)d_in[8];
    const float* gb2  = (const float*)d_in[9];
    const float* pos  = (const float*)d_in[10];
    const float* anw  = (const float*)d_in[11];
    const float* anb  = (const float*)d_in[12];
    const float* inw  = (const float*)d_in[13];
    const float* inb  = (const float*)d_in[14];
    const float* oww  = (const float*)d_in[15];
    const float* owb  = (const float*)d_in[16];
    const float* fnw  = (const float*)d_in[17];
    const float* fnb  = (const float*)d_in[18];
    const float* w1   = (const float*)d_in[19];
    const float* b1   = (const float*)d_in[20];
    const float* w2   = (const float*)d_in[21];
    const float* b2   = (const float*)d_in[22];
    const float* tlnw = (const float*)d_in[23];
    const float* tlnb = (const float*)d_in[24];
    const float* tw1  = (const float*)d_in[25];
    const float* tb1  = (const float*)d_in[26];
    const float* tw2  = (const float*)d_in[27];
    const float* tb2  = (const float*)d_in[28];
    float* out = (float*)d_out;

    // ---- workspace layout (floats) — base 79,175,712; mirror +67,108,864 ----
    float* ws    = (float*)d_ws;
    float* wbuf  = ws;                               // 2048
    int*   cnt3  = (int*)(wbuf + 2048);              // 16
    int*   roff  = cnt3 + 16;                        // 16
    int*   idxb  = roff + 16;                        // 4*1536 = 6144
    float* flatb = (float*)(idxb + 4 * BT_);         // 512*3072
    float* glin  = flatb + (long)B_ * 3072;          // 512*1024
    float* seq   = glin + (long)B_ * 1024;           // 6*PROWS*1024
    float* st    = seq + 6L * PROWS * 1024;          // TROWS*1024
    unsigned short* xnB  = (unsigned short*)(st + (long)TROWS * 1024);  // TROWS*1024 bf16
    unsigned short* bigB = xnB + (long)TROWS * 1024;                     // TROWS*3072 bf16
    unsigned short* Fbuf = bigB;                               // tri/FFN hidden bf16 (PROWS*2048)
    unsigned short* axB  = xnB;                                // compact attn-out overlaps xnB head
    float* Obuf = (float*)(bigB + 16777216);                   // tri out f32 (PROWS*3072)
    float* stL  = seq + 5L * PROWS * 1024;                     // PROWS*1024 f32 (slab 5 free in-step)
    if (ws_size < 79175712UL * sizeof(float)) return;

    // ---- optional bf16 weight mirror (585.1 MB total) ----
    const bool mir = (ws_size >= 146284576UL * sizeof(float));
    unsigned short* wM   = (unsigned short*)(ws + 79175712UL);
    unsigned short* winM = wM;                                   // [E][L][3072][1024]
    unsigned short* wowM = winM + (long)E_ * L_ * 3072 * 1024;   // [E][L][1024][1024]
    unsigned short* w1M  = wowM + (long)E_ * L_ * 1024 * 1024;   // [E][L][4096][1024]
    unsigned short* w2M  = w1M  + (long)E_ * L_ * 4096 * 1024;   // [E][L][1024][4096]
    unsigned short* t1M  = w2M  + (long)E_ * L_ * 1024 * 4096;   // [E][2048][1024]
    unsigned short* t2M  = t1M  + (long)E_ * 2048 * 1024;        // [E][3072][2048]

    // ---- gating (pure f32, bit-stable) ----
    build_flat_kernel<<<B_ * 3, 256, 0, stream>>>(iw, ia, ir, flatb);
    gemm_f32<<<dim3(16, 8), 256, 0, stream>>>(flatb, gw1, gb1, nullptr, glin, B_, 1024, 3072, 0);
    ln_gate<<<B_, 256, 0, stream>>>(glin, glnw, glnb, glin);
    gate_kernel<<<B_ / 4, 256, 0, stream>>>(glin, gw2, gb2, wbuf);
    build_idx2_kernel<<<1, 64, 0, stream>>>(wbuf, idxb, cnt3, roff);

    zero_kernel<<<2048, 256, 0, stream>>>(out, (long)ND_ * STEPS_ * 3 * B_ * 1024 / 4);

    if (mir) {
        cvt_bf16_kernel<<<2048, 256, 0, stream>>>(inw, winM, (long)E_ * L_ * 3072 * 1024 / 4);
        cvt_bf16_kernel<<<2048, 256, 0, stream>>>(oww, wowM, (long)E_ * L_ * 1024 * 1024 / 4);
        cvt_bf16_kernel<<<2048, 256, 0, stream>>>(w1,  w1M,  (long)E_ * L_ * 4096 * 1024 / 4);
        cvt_bf16_kernel<<<2048, 256, 0, stream>>>(w2,  w2M,  (long)E_ * L_ * 1024 * 4096 / 4);
        cvt_bf16_kernel<<<2048, 256, 0, stream>>>(tw1, t1M,  (long)E_ * 2048 * 1024 / 4);
        cvt_bf16_kernel<<<2048, 256, 0, stream>>>(tw2, t2M,  (long)E_ * 3072 * 2048 / 4);
    }

    seq0_bt<<<PROWS, 256, 0, stream>>>(iw, ia, ir, doff, idxb, cnt3, roff, seq);

    for (int t = 0; t < STEPS_; ++t) {
        const int T = t + 1;
        const int MT = PROWS * T;

        // ===== layer 0 — FULL (all T tokens; layer 1 needs everyone's K/V) =====
        {
            const int l = 0;
            ln_st_bt<<<MT, 256, 0, stream>>>(seq, pos, st,
                                             anw + l * 1024, anb + l * 1024,
                                             (long)L_ * 1024, xnB, roff, T);
            G<0, 1>(mir, dim3(24, MT / 128), stream, xnB,
                    inw + (long)l * 3072 * 1024, winM + (long)l * 3072 * 1024,
                    (long)L_ * 3072 * 1024, 1024,
                    inb + l * 3072, (long)L_ * 3072, nullptr, 0, bigB, 3072, 1024, roff, T);
            switch (T) {
                case 1: attn_bt<1><<<PROWS * 8 * 1 / 4, 256, 0, stream>>>(bigB, xnB, roff); break;
                case 2: attn_bt<2><<<PROWS * 8 * 2 / 4, 256, 0, stream>>>(bigB, xnB, roff); break;
                case 3: attn_bt<3><<<PROWS * 8 * 3 / 4, 256, 0, stream>>>(bigB, xnB, roff); break;
                case 4: attn_bt<4><<<PROWS * 8 * 4 / 4, 256, 0, stream>>>(bigB, xnB, roff); break;
                case 5: attn_bt<5><<<PROWS * 8 * 5 / 4, 256, 0, stream>>>(bigB, xnB, roff); break;
            }
            G<0, 0>(mir, dim3(8, MT / 128), stream, xnB,
                    oww + (long)l * 1024 * 1024, wowM + (long)l * 1024 * 1024,
                    (long)L_ * 1024 * 1024, 1024,
                    owb + l * 1024, (long)L_ * 1024, st, 1024, st, 1024, 1024, roff, T);
            ln_bt<<<MT, 256, 0, stream>>>(st, 1024, fnw + l * 1024, fnb + l * 1024,
                                          (long)L_ * 1024, xnB, roff, T);
            for (int c = 0; c < 2; ++c) {
                G<1, 1>(mir, dim3(16, MT / 128), stream, xnB,
                        w1 + (long)l * 4096 * 1024 + (long)c * 2048 * 1024,
                        w1M + (long)l * 4096 * 1024 + (long)c * 2048 * 1024,
                        (long)L_ * 4096 * 1024, 1024,
                        b1 + l * 4096 + c * 2048, (long)L_ * 4096, nullptr, 0, bigB, 2048, 1024, roff, T);
                G<0, 0>(mir, dim3(8, MT / 128), stream, bigB,
                        w2 + (long)l * 1024 * 4096 + (long)c * 2048,
                        w2M + (long)l * 1024 * 4096 + (long)c * 2048,
                        (long)L_ * 1024 * 4096, 4096,
                        (c == 0) ? (b2 + l * 1024) : nullptr, (long)L_ * 1024,
                        st, 1024, st, 1024, 2048, roff, T);
            }
        }

        // ===== layer 1 — o-proj/FFN only for the LAST token of each prow =====
        {
            const int l = 1;
            ln_bt<<<MT, 256, 0, stream>>>(st, 1024, anw + l * 1024, anb + l * 1024,
                                          (long)L_ * 1024, xnB, roff, T);
            G<0, 1>(mir, dim3(24, MT / 128), stream, xnB,
                    inw + (long)l * 3072 * 1024, winM + (long)l * 3072 * 1024,
                    (long)L_ * 3072 * 1024, 1024,
                    inb + l * 3072, (long)L_ * 3072, nullptr, 0, bigB, 3072, 1024, roff, T);
            switch (T) {
                case 1: attn_last<1><<<PROWS * 8 / 4, 256, 0, stream>>>(bigB, axB, roff); break;
                case 2: attn_last<2><<<PROWS * 8 / 4, 256, 0, stream>>>(bigB, axB, roff); break;
                case 3: attn_last<3><<<PROWS * 8 / 4, 256, 0, stream>>>(bigB, axB, roff); break;
                case 4: attn_last<4><<<PROWS * 8 / 4, 256, 0, stream>>>(bigB, axB, roff); break;
                case 5: attn_last<5><<<PROWS * 8 / 4, 256, 0, stream>>>(bigB, axB, roff); break;
            }
            G<0, 0>(mir, dim3(8, PROWS / 128), stream, axB,
                    oww + (long)l * 1024 * 1024, wowM + (long)l * 1024 * 1024,
                    (long)L_ * 1024 * 1024, 1024,
                    owb + l * 1024, (long)L_ * 1024,
                    st + (long)t * 1024, (long)T * 1024, stL, 1024, 1024, roff, 1);
            ln_bt<<<PROWS, 256, 0, stream>>>(stL, 1024, fnw + l * 1024, fnb + l * 1024,
                                             (long)L_ * 1024, xnB, roff, 1);
            for (int c = 0; c < 2; ++c) {
                G<1, 1>(mir, dim3(16, PROWS / 128), stream, xnB,
                        w1 + (long)l * 4096 * 1024 + (long)c * 2048 * 1024,
                        w1M + (long)l * 4096 * 1024 + (long)c * 2048 * 1024,
                        (long)L_ * 4096 * 1024, 1024,
                        b1 + l * 4096 + c * 2048, (long)L_ * 4096, nullptr, 0, Fbuf, 2048, 1024, roff, 1);
                G<0, 0>(mir, dim3(8, PROWS / 128), stream, Fbuf,
                        w2 + (long)l * 1024 * 4096 + (long)c * 2048,
                        w2M + (long)l * 1024 * 4096 + (long)c * 2048,
                        (long)L_ * 1024 * 4096, 4096,
                        (c == 0) ? (b2 + l * 1024) : nullptr, (long)L_ * 1024,
                        stL, 1024, stL, 1024, 2048, roff, 1);
            }
        }

        // triplet projection of last token (stL) -> next seq entry
        ln_bt<<<PROWS, 256, 0, stream>>>(stL, 1024, tlnw, tlnb, 1024, xnB, roff, 1);
        G<1, 1>(mir, dim3(16, PROWS / 128), stream, xnB,
                tw1, t1M, 2048L * 1024, 1024, tb1, 2048, nullptr, 0, Fbuf, 2048, 1024, roff, 1);
        G<0, 0>(mir, dim3(24, PROWS / 128), stream, Fbuf,
                tw2, t2M, 3072L * 2048, 2048, tb2, 3072, nullptr, 0, Obuf, 3072, 2048, roff, 1);
        mean3_bt<<<PROWS, 256, 0, stream>>>(Obuf, seq + (long)(t + 1) * PROWS * 1024, roff);
    }
    // final triplet projection over embs = seq[1..5], one slab at a time
    for (int s = 0; s < STEPS_; ++s) {
        ln_bt<<<PROWS, 256, 0, stream>>>(seq + (long)(s + 1) * PROWS * 1024, 1024,
                                         tlnw, tlnb, 1024, xnB, roff, 1);
        G<1, 1>(mir, dim3(16, PROWS / 128), stream, xnB,
                tw1, t1M, 2048L * 1024, 1024, tb1, 2048, nullptr, 0, Fbuf, 2048, 1024, roff, 1);
        G<0, 0>(mir, dim3(24, PROWS / 128), stream, Fbuf,
                tw2, t2M, 3072L * 2048, 2048, tb2, 3072, nullptr, 0, Obuf, 3072, 2048, roff, 1);
        for (int e = 0; e < E_; ++e)
            scatter_bt<<<BT_, 256, 0, stream>>>(Obuf, wbuf, idxb, cnt3, roff, out, e, s);
    }
}

// Round 14
// 6108.576 us; speedup vs baseline: 1.1352x; 1.1352x over previous
//
#include <hip/hip_runtime.h>
#include <hip/hip_bf16.h>
#include <cstdint>

#define B_  512
#define D_  1024
#define E_  4
#define L_  2
#define FF_ 4096
#define ND_ 3
#define BT_ 1536   // ND_*B_
#define STEPS_ 5
#define H_ 8
#define PROWS 3584         // max sum of pad128(3*cnt_e) over experts
#define TROWS (PROWS * STEPS_)

typedef __attribute__((ext_vector_type(8))) __bf16 bf16x8;
typedef __attribute__((ext_vector_type(8))) unsigned short u16x8;
typedef __attribute__((ext_vector_type(4))) float f32x4;

static __device__ __forceinline__ float gelu_f(float x) {
    return 0.5f * x * (1.0f + erff(x * 0.70710678118654752f));
}

static __device__ __forceinline__ unsigned short f2bf(float x) {
    unsigned u = __builtin_bit_cast(unsigned, x);
    u = (u + 0x7fff + ((u >> 16) & 1)) >> 16;   // RNE
    return (unsigned short)u;
}

static __device__ __forceinline__ float bf2f(unsigned short us) {
    unsigned v = (unsigned)us << 16;
    return __builtin_bit_cast(float, v);
}

static __device__ __forceinline__ void gload16(const void* g, void* l) {
    __builtin_amdgcn_global_load_lds(
        (const __attribute__((address_space(1))) unsigned int*)g,
        (__attribute__((address_space(3))) unsigned int*)l, 16, 0, 0);
}

static __device__ __forceinline__ int pad128(int x) { return (x + 127) & ~127; }

// =====================================================================
// Variant A (fallback): in-kernel W f32->bf16 conversion (round-12 proven).
// =====================================================================
template<int ACT, int OUTBF>
__global__ __launch_bounds__(512) void gemm_wf32(
    const unsigned short* __restrict__ A,
    const float* __restrict__ Wb, long wstride, int LDA,
    const float* __restrict__ biasb, long bstride,
    const float* __restrict__ R, long Rld, void* __restrict__ Cout, int N, int K,
    const int* __restrict__ roff, int T)
{
    const long row0 = (long)blockIdx.y * 128;
    if ((int)row0 >= roff[4] * T) return;
    int e = 0;
    while (e < 3 && (int)row0 >= roff[e + 1] * T) ++e;
    const float* W = Wb + (long)e * wstride;
    const float* bias = biasb ? (biasb + (long)e * bstride) : nullptr;

    __shared__ __align__(16) unsigned short As[2 * 128 * 32];
    __shared__ __align__(16) unsigned short Bs[2 * 128 * 32];
    const int t = threadIdx.x;
    const int lane = t & 63;
    const int wid = t >> 6;
    const int wr = wid >> 1;
    const int wc = wid & 1;
    const long col0 = (long)blockIdx.x * 128;
    const int l15 = lane & 15, l4 = lane >> 4;

    f32x4 acc[2][4] = {};

    const unsigned short* Ag = A + (row0 + (t >> 2)) * (long)K + (t & 3) * 8;
    char* AdBase = (char*)As + t * 16;
    const float* Wg = W + (long)(col0 + (t >> 2)) * LDA + (t & 3) * 8;

    const int K32 = K >> 5;
    float4 w0, w1;

    gload16(Ag, AdBase);
    w0 = *(const float4*)(Wg);
    w1 = *(const float4*)(Wg + 4);
    {
        u16x8 p = {f2bf(w0.x), f2bf(w0.y), f2bf(w0.z), f2bf(w0.w),
                   f2bf(w1.x), f2bf(w1.y), f2bf(w1.z), f2bf(w1.w)};
        *(u16x8*)((char*)Bs + t * 16) = p;
    }
    if (K32 > 1) {
        w0 = *(const float4*)(Wg + 32);
        w1 = *(const float4*)(Wg + 36);
    }
    __syncthreads();

    for (int j = 0; j < K32; ++j) {
        const int cur = j & 1;
        const int nxt = cur ^ 1;
        if (j + 1 < K32) {
            gload16(Ag + ((j + 1) << 5), AdBase + nxt * 8192);
            u16x8 p = {f2bf(w0.x), f2bf(w0.y), f2bf(w0.z), f2bf(w0.w),
                       f2bf(w1.x), f2bf(w1.y), f2bf(w1.z), f2bf(w1.w)};
            *(u16x8*)((char*)Bs + nxt * 8192 + t * 16) = p;
        }
        if (j + 2 < K32) {
            const int k2 = (j + 2) << 5;
            w0 = *(const float4*)(Wg + k2);
            w1 = *(const float4*)(Wg + k2 + 4);
        }
        bf16x8 af[2], bf[4];
        #pragma unroll
        for (int m = 0; m < 2; ++m)
            af[m] = *(const bf16x8*)((const char*)As + cur * 8192 + (wr * 32 + m * 16 + l15) * 64 + l4 * 16);
        #pragma unroll
        for (int n = 0; n < 4; ++n)
            bf[n] = *(const bf16x8*)((const char*)Bs + cur * 8192 + (wc * 64 + n * 16 + l15) * 64 + l4 * 16);
        __builtin_amdgcn_s_setprio(1);
        #pragma unroll
        for (int m = 0; m < 2; ++m)
            #pragma unroll
            for (int n = 0; n < 4; ++n)
                acc[m][n] = __builtin_amdgcn_mfma_f32_16x16x32_bf16(af[m], bf[n], acc[m][n], 0, 0, 0);
        __builtin_amdgcn_s_setprio(0);
        __syncthreads();
    }

    #pragma unroll
    for (int n = 0; n < 4; ++n) {
        const long col = col0 + wc * 64 + n * 16 + l15;
        const float bn = bias ? bias[col] : 0.0f;
        #pragma unroll
        for (int m = 0; m < 2; ++m) {
            const long rbase = row0 + wr * 32 + m * 16 + l4 * 4;
            #pragma unroll
            for (int r = 0; r < 4; ++r) {
                float o = acc[m][n][r] + bn;
                if (ACT) o = gelu_f(o);
                const long coff = (rbase + r) * (long)N + col;
                if (R) o += R[(rbase + r) * Rld + col];
                if (OUTBF) ((unsigned short*)Cout)[coff] = f2bf(o);
                else       ((float*)Cout)[coff] = o;
            }
        }
    }
}

// =====================================================================
// Variant B (mirror): both operands bf16 via pure global_load_lds DMA.
// Per K-step: 2 gloads + 8 MFMA + 1 barrier — no VALU staging at all.
// W values are the same RNE-converted bf16 -> output bit-identical to A.
// =====================================================================
template<int ACT, int OUTBF>
__global__ __launch_bounds__(512) void gemm_bb(
    const unsigned short* __restrict__ A,
    const unsigned short* __restrict__ Wb, long wstride, int LDA,
    const float* __restrict__ biasb, long bstride,
    const float* __restrict__ R, long Rld, void* __restrict__ Cout, int N, int K,
    const int* __restrict__ roff, int T)
{
    const long row0 = (long)blockIdx.y * 128;
    if ((int)row0 >= roff[4] * T) return;
    int e = 0;
    while (e < 3 && (int)row0 >= roff[e + 1] * T) ++e;
    const unsigned short* W = Wb + (long)e * wstride;
    const float* bias = biasb ? (biasb + (long)e * bstride) : nullptr;

    __shared__ __align__(16) unsigned short As[2 * 128 * 32];
    __shared__ __align__(16) unsigned short Bs[2 * 128 * 32];
    const int t = threadIdx.x;
    const int lane = t & 63;
    const int wid = t >> 6;
    const int wr = wid >> 1;
    const int wc = wid & 1;
    const long col0 = (long)blockIdx.x * 128;
    const int l15 = lane & 15, l4 = lane >> 4;

    f32x4 acc[2][4] = {};

    const unsigned short* Ag = A + (row0 + (t >> 2)) * (long)K + (t & 3) * 8;
    const unsigned short* Wg = W + (long)(col0 + (t >> 2)) * LDA + (t & 3) * 8;
    char* AdBase = (char*)As + t * 16;
    char* BdBase = (char*)Bs + t * 16;

    const int K32 = K >> 5;

    gload16(Ag, AdBase);
    gload16(Wg, BdBase);
    __syncthreads();

    for (int j = 0; j < K32; ++j) {
        const int cur = j & 1;
        const int nxt = cur ^ 1;
        if (j + 1 < K32) {
            const int k1 = (j + 1) << 5;
            gload16(Ag + k1, AdBase + nxt * 8192);
            gload16(Wg + k1, BdBase + nxt * 8192);
        }
        bf16x8 af[2], bf[4];
        #pragma unroll
        for (int m = 0; m < 2; ++m)
            af[m] = *(const bf16x8*)((const char*)As + cur * 8192 + (wr * 32 + m * 16 + l15) * 64 + l4 * 16);
        #pragma unroll
        for (int n = 0; n < 4; ++n)
            bf[n] = *(const bf16x8*)((const char*)Bs + cur * 8192 + (wc * 64 + n * 16 + l15) * 64 + l4 * 16);
        __builtin_amdgcn_s_setprio(1);
        #pragma unroll
        for (int m = 0; m < 2; ++m)
            #pragma unroll
            for (int n = 0; n < 4; ++n)
                acc[m][n] = __builtin_amdgcn_mfma_f32_16x16x32_bf16(af[m], bf[n], acc[m][n], 0, 0, 0);
        __builtin_amdgcn_s_setprio(0);
        __syncthreads();
    }

    #pragma unroll
    for (int n = 0; n < 4; ++n) {
        const long col = col0 + wc * 64 + n * 16 + l15;
        const float bn = bias ? bias[col] : 0.0f;
        #pragma unroll
        for (int m = 0; m < 2; ++m) {
            const long rbase = row0 + wr * 32 + m * 16 + l4 * 4;
            #pragma unroll
            for (int r = 0; r < 4; ++r) {
                float o = acc[m][n][r] + bn;
                if (ACT) o = gelu_f(o);
                const long coff = (rbase + r) * (long)N + col;
                if (R) o += R[(rbase + r) * Rld + col];
                if (OUTBF) ((unsigned short*)Cout)[coff] = f2bf(o);
                else       ((float*)Cout)[coff] = o;
            }
        }
    }
}

// ---------------- f32 GEMM (gating only — bit-stable expert pick) ----------------
__global__ __launch_bounds__(256) void gemm_f32(
    const float* __restrict__ A, const float* __restrict__ W,
    const float* __restrict__ bias, const float* __restrict__ R,
    float* __restrict__ C, int M, int N, int K, int act)
{
    __shared__ float As[16][68];
    __shared__ float Bs[16][68];
    const int tid = threadIdx.x;
    const int tx = tid & 15;
    const int ty = tid >> 4;
    const long row0 = (long)blockIdx.y * 64;
    const long col0 = (long)blockIdx.x * 64;
    const int lr = tid >> 2;
    const int lq = (tid & 3) << 2;
    const float* Ap = A + (row0 + lr) * (long)K + lq;
    const float* Wp = W + (col0 + lr) * (long)K + lq;
    float acc[4][4] = {};
    for (int k0 = 0; k0 < K; k0 += 16) {
        const float4 av = *(const float4*)(Ap + k0);
        const float4 wv = *(const float4*)(Wp + k0);
        __syncthreads();
        As[lq + 0][lr] = av.x; As[lq + 1][lr] = av.y;
        As[lq + 2][lr] = av.z; As[lq + 3][lr] = av.w;
        Bs[lq + 0][lr] = wv.x; Bs[lq + 1][lr] = wv.y;
        Bs[lq + 2][lr] = wv.z; Bs[lq + 3][lr] = wv.w;
        __syncthreads();
        #pragma unroll
        for (int kk = 0; kk < 16; ++kk) {
            const float4 a4 = *(const float4*)&As[kk][ty << 2];
            const float4 b4 = *(const float4*)&Bs[kk][tx << 2];
            const float aa[4] = {a4.x, a4.y, a4.z, a4.w};
            const float bb[4] = {b4.x, b4.y, b4.z, b4.w};
            #pragma unroll
            for (int i = 0; i < 4; ++i)
                #pragma unroll
                for (int j = 0; j < 4; ++j)
                    acc[i][j] = fmaf(aa[i], bb[j], acc[i][j]);
        }
    }
    const float4 bv = *(const float4*)(bias + col0 + (tx << 2));
    const float bb[4] = {bv.x, bv.y, bv.z, bv.w};
    #pragma unroll
    for (int i = 0; i < 4; ++i) {
        const long row = row0 + (ty << 2) + i;
        const long off = row * (long)N + col0 + (tx << 2);
        float o[4];
        #pragma unroll
        for (int j = 0; j < 4; ++j) {
            o[j] = acc[i][j] + bb[j];
            if (act) o[j] = gelu_f(o[j]);
        }
        if (R) {
            const float4 rv = *(const float4*)(R + off);
            o[0] += rv.x; o[1] += rv.y; o[2] += rv.z; o[3] += rv.w;
        }
        *(float4*)(C + off) = make_float4(o[0], o[1], o[2], o[3]);
    }
}

// ---------------- LayerNorm (plain, gating, fused GELU) ----------------
__global__ __launch_bounds__(256) void ln_gate(
    const float* __restrict__ X,
    const float* __restrict__ gamma, const float* __restrict__ beta,
    float* __restrict__ Y)
{
    const long r = blockIdx.x;
    const int tid = threadIdx.x;
    __shared__ float red[8];
    const float4 v = *(const float4*)(X + (r << 10) + (tid << 2));
    float s = v.x + v.y + v.z + v.w;
    #pragma unroll
    for (int off = 32; off; off >>= 1) s += __shfl_xor(s, off);
    if ((tid & 63) == 0) red[tid >> 6] = s;
    __syncthreads();
    const float mean = (red[0] + red[1] + red[2] + red[3]) * (1.0f / 1024.0f);
    const float dx = v.x - mean, dy = v.y - mean, dz = v.z - mean, dw = v.w - mean;
    float s2 = dx * dx + dy * dy + dz * dz + dw * dw;
    #pragma unroll
    for (int off = 32; off; off >>= 1) s2 += __shfl_xor(s2, off);
    if ((tid & 63) == 0) red[4 + (tid >> 6)] = s2;
    __syncthreads();
    const float var = (red[4] + red[5] + red[6] + red[7]) * (1.0f / 1024.0f);
    const float inv = rsqrtf(var + 1e-5f);
    const float4 g = *(const float4*)(gamma + (tid << 2));
    const float4 b = *(const float4*)(beta + (tid << 2));
    float o0 = gelu_f(dx * inv * g.x + b.x);
    float o1 = gelu_f(dy * inv * g.y + b.y);
    float o2 = gelu_f(dz * inv * g.z + b.z);
    float o3 = gelu_f(dw * inv * g.w + b.w);
    *(float4*)(Y + (r << 10) + (tid << 2)) = make_float4(o0, o1, o2, o3);
}

// ---------------- LayerNorm, expert-batched gamma/beta, bf16 out ----------------
__global__ __launch_bounds__(256) void ln_bt(
    const float* __restrict__ X, long xstride,
    const float* __restrict__ gammaB, const float* __restrict__ betaB, long gstride,
    unsigned short* __restrict__ Y, const int* __restrict__ roff, int T)
{
    const long r = blockIdx.x;
    if ((int)r >= roff[4] * T) return;
    int e = 0;
    while (e < 3 && (int)r >= roff[e + 1] * T) ++e;
    const float* gamma = gammaB + (long)e * gstride;
    const float* beta  = betaB  + (long)e * gstride;

    const int tid = threadIdx.x;
    __shared__ float red[8];
    const float4 v = *(const float4*)(X + r * xstride + (tid << 2));
    float s = v.x + v.y + v.z + v.w;
    #pragma unroll
    for (int off = 32; off; off >>= 1) s += __shfl_xor(s, off);
    if ((tid & 63) == 0) red[tid >> 6] = s;
    __syncthreads();
    const float mean = (red[0] + red[1] + red[2] + red[3]) * (1.0f / 1024.0f);
    const float dx = v.x - mean, dy = v.y - mean, dz = v.z - mean, dw = v.w - mean;
    float s2 = dx * dx + dy * dy + dz * dz + dw * dw;
    #pragma unroll
    for (int off = 32; off; off >>= 1) s2 += __shfl_xor(s2, off);
    if ((tid & 63) == 0) red[4 + (tid >> 6)] = s2;
    __syncthreads();
    const float var = (red[4] + red[5] + red[6] + red[7]) * (1.0f / 1024.0f);
    const float inv = rsqrtf(var + 1e-5f);
    const float4 g = *(const float4*)(gamma + (tid << 2));
    const float4 b = *(const float4*)(beta + (tid << 2));
    const float o0 = dx * inv * g.x + b.x;
    const float o1 = dy * inv * g.y + b.y;
    const float o2 = dz * inv * g.z + b.z;
    const float o3 = dw * inv * g.w + b.w;
    ushort4 o = make_ushort4(f2bf(o0), f2bf(o1), f2bf(o2), f2bf(o3));
    *(ushort4*)(Y + (r << 10) + (tid << 2)) = o;
}

// ---------------- FUSED: st = seq+pos; write st; LayerNorm(st) -> bf16 Y ----------------
__global__ __launch_bounds__(256) void ln_st_bt(
    const float* __restrict__ seq, const float* __restrict__ posb,
    float* __restrict__ st,
    const float* __restrict__ gammaB, const float* __restrict__ betaB, long gstride,
    unsigned short* __restrict__ Y, const int* __restrict__ roff, int T)
{
    const int r = blockIdx.x;           // trow in [0, PROWS*T)
    const int prow = r / T;
    if (prow >= roff[4]) return;
    int e = 0;
    while (e < 3 && prow >= roff[e + 1]) ++e;
    const int tau = r - prow * T;
    const float* gamma = gammaB + (long)e * gstride;
    const float* beta  = betaB  + (long)e * gstride;

    const int tid = threadIdx.x;
    const int d4 = tid << 2;
    __shared__ float red[8];
    const float4 sv = *(const float4*)(seq + (((long)tau * PROWS + prow) << 10) + d4);
    const float4 pv = *(const float4*)(posb + (((long)e * 10 + tau) << 10) + d4);
    const float4 v = make_float4(sv.x + pv.x, sv.y + pv.y, sv.z + pv.z, sv.w + pv.w);
    *(float4*)(st + ((long)r << 10) + d4) = v;

    float s = v.x + v.y + v.z + v.w;
    #pragma unroll
    for (int off = 32; off; off >>= 1) s += __shfl_xor(s, off);
    if ((tid & 63) == 0) red[tid >> 6] = s;
    __syncthreads();
    const float mean = (red[0] + red[1] + red[2] + red[3]) * (1.0f / 1024.0f);
    const float dx = v.x - mean, dy = v.y - mean, dz = v.z - mean, dw = v.w - mean;
    float s2 = dx * dx + dy * dy + dz * dz + dw * dw;
    #pragma unroll
    for (int off = 32; off; off >>= 1) s2 += __shfl_xor(s2, off);
    if ((tid & 63) == 0) red[4 + (tid >> 6)] = s2;
    __syncthreads();
    const float var = (red[4] + red[5] + red[6] + red[7]) * (1.0f / 1024.0f);
    const float inv = rsqrtf(var + 1e-5f);
    const float4 g = *(const float4*)(gamma + d4);
    const float4 b = *(const float4*)(beta + d4);
    const float o0 = dx * inv * g.x + b.x;
    const float o1 = dy * inv * g.y + b.y;
    const float o2 = dz * inv * g.z + b.z;
    const float o3 = dw * inv * g.w + b.w;
    ushort4 o = make_ushort4(f2bf(o0), f2bf(o1), f2bf(o2), f2bf(o3));
    *(ushort4*)(Y + ((long)r << 10) + d4) = o;
}

// ---------------- attention (all queries): bf16 qkv in, bf16 out ----------------
template<int TT>
__global__ __launch_bounds__(256) void attn_bt(
    const unsigned short* __restrict__ qkv, unsigned short* __restrict__ o,
    const int* __restrict__ roff)
{
    const int item = (int)(((long)blockIdx.x * 256 + threadIdx.x) >> 6);
    const int lane = threadIdx.x & 63;
    const int tq = item % TT;
    const int h  = (item / TT) & 7;
    const int i  = item / (TT * 8);
    if (i >= roff[4]) return;
    const unsigned short* base = qkv + (long)i * TT * 3072;
    const unsigned short* q = base + (long)tq * 3072 + h * 128;
    const float q0 = bf2f(q[lane]), q1 = bf2f(q[lane + 64]);
    float s[TT];
    const float scale = 0.088388347648318447f;  // 1/sqrt(128)
    #pragma unroll
    for (int tk = 0; tk < TT; ++tk) {
        const unsigned short* k = base + (long)tk * 3072 + 1024 + h * 128;
        float p = q0 * bf2f(k[lane]) + q1 * bf2f(k[lane + 64]);
        #pragma unroll
        for (int off = 32; off; off >>= 1) p += __shfl_xor(p, off);
        s[tk] = p * scale;
    }
    float m = s[0];
    #pragma unroll
    for (int tk = 1; tk < TT; ++tk) m = fmaxf(m, s[tk]);
    float den = 0.f;
    #pragma unroll
    for (int tk = 0; tk < TT; ++tk) { s[tk] = expf(s[tk] - m); den += s[tk]; }
    float o0 = 0.f, o1 = 0.f;
    #pragma unroll
    for (int tk = 0; tk < TT; ++tk) {
        const unsigned short* v = base + (long)tk * 3072 + 2048 + h * 128;
        o0 += s[tk] * bf2f(v[lane]); o1 += s[tk] * bf2f(v[lane + 64]);
    }
    const float id = 1.0f / den;
    unsigned short* op = o + ((long)i * TT + tq) * 1024 + h * 128;
    op[lane] = f2bf(o0 * id); op[lane + 64] = f2bf(o1 * id);
}

// ---------------- attention (LAST query only): compact out (PROWS x 1024) ----------------
template<int TT>
__global__ __launch_bounds__(256) void attn_last(
    const unsigned short* __restrict__ qkv, unsigned short* __restrict__ o,
    const int* __restrict__ roff)
{
    const int item = (int)(((long)blockIdx.x * 256 + threadIdx.x) >> 6);
    const int lane = threadIdx.x & 63;
    const int h  = item & 7;
    const int i  = item >> 3;
    if (i >= roff[4]) return;
    const unsigned short* base = qkv + (long)i * TT * 3072;
    const unsigned short* q = base + (long)(TT - 1) * 3072 + h * 128;
    const float q0 = bf2f(q[lane]), q1 = bf2f(q[lane + 64]);
    float s[TT];
    const float scale = 0.088388347648318447f;
    #pragma unroll
    for (int tk = 0; tk < TT; ++tk) {
        const unsigned short* k = base + (long)tk * 3072 + 1024 + h * 128;
        float p = q0 * bf2f(k[lane]) + q1 * bf2f(k[lane + 64]);
        #pragma unroll
        for (int off = 32; off; off >>= 1) p += __shfl_xor(p, off);
        s[tk] = p * scale;
    }
    float m = s[0];
    #pragma unroll
    for (int tk = 1; tk < TT; ++tk) m = fmaxf(m, s[tk]);
    float den = 0.f;
    #pragma unroll
    for (int tk = 0; tk < TT; ++tk) { s[tk] = expf(s[tk] - m); den += s[tk]; }
    float o0 = 0.f, o1 = 0.f;
    #pragma unroll
    for (int tk = 0; tk < TT; ++tk) {
        const unsigned short* v = base + (long)tk * 3072 + 2048 + h * 128;
        o0 += s[tk] * bf2f(v[lane]); o1 += s[tk] * bf2f(v[lane + 64]);
    }
    const float id = 1.0f / den;
    unsigned short* op = o + (long)i * 1024 + h * 128;
    op[lane] = f2bf(o0 * id); op[lane + 64] = f2bf(o1 * id);
}

// ---------------- gating ----------------
__global__ __launch_bounds__(256) void gate_kernel(
    const float* __restrict__ g, const float* __restrict__ gw2,
    const float* __restrict__ gb2, float* __restrict__ wout)
{
    const int b = (int)(((long)blockIdx.x * 256 + threadIdx.x) >> 6);
    const int lane = threadIdx.x & 63;
    float acc[E_] = {};
    const float* row = g + (long)b * 1024;
    for (int d = lane; d < 1024; d += 64) {
        const float x = row[d];
        #pragma unroll
        for (int j = 0; j < E_; ++j) acc[j] += x * gw2[j * 1024 + d];
    }
    #pragma unroll
    for (int j = 0; j < E_; ++j) {
        #pragma unroll
        for (int off = 32; off; off >>= 1) acc[j] += __shfl_xor(acc[j], off);
        acc[j] += gb2[j];
    }
    int i0 = 0; float v0 = acc[0];
    #pragma unroll
    for (int j = 1; j < E_; ++j) if (acc[j] > v0) { v0 = acc[j]; i0 = j; }
    int i1 = -1; float v1 = -1e30f;
    #pragma unroll
    for (int j = 0; j < E_; ++j) if (j != i0 && acc[j] > v1) { v1 = acc[j]; i1 = j; }
    const float p1 = expf(v1 - v0);
    const float den = 1.0f + p1;
    const float g0 = 1.0f / den, g1 = p1 / den;
    if (lane < E_) wout[b * E_ + lane] = (lane == i0) ? g0 : (lane == i1) ? g1 : 0.0f;
}

// single block: per-expert compact lists + packed-row offsets
__global__ __launch_bounds__(64) void build_idx2_kernel(
    const float* __restrict__ wbuf, int* __restrict__ idx,
    int* __restrict__ cnt3, int* __restrict__ roff)
{
    const int lane = threadIdx.x;
    int pads[E_];
    for (int e = 0; e < E_; ++e) {
        int* my = idx + e * BT_;
        int base = 0;
        for (int chunk = 0; chunk < 8; ++chunk) {
            const int b = chunk * 64 + lane;
            const bool sel = wbuf[b * E_ + e] > 0.0f;
            const unsigned long long mask = __ballot(sel);
            const int pos = base + (int)__popcll(mask & ((1ull << lane) - 1ull));
            if (sel) {
                my[3 * pos + 0] = b;
                my[3 * pos + 1] = 512 + b;
                my[3 * pos + 2] = 1024 + b;
            }
            base += (int)__popcll(mask);
        }
        if (lane == 0) cnt3[e] = 3 * base;
        pads[e] = pad128(3 * base);
    }
    if (lane == 0) {
        roff[0] = 0;
        for (int e = 0; e < E_; ++e) roff[e + 1] = roff[e] + pads[e];
    }
}

// packed seq0: prow -> (e, j); gather or zero
__global__ __launch_bounds__(256) void seq0_bt(
    const float* __restrict__ w, const float* __restrict__ a,
    const float* __restrict__ rr, const float* __restrict__ doff,
    const int* __restrict__ idx, const int* __restrict__ cnt3,
    const int* __restrict__ roff, float* __restrict__ seq0)
{
    const int prow = blockIdx.x;
    if (prow >= roff[4]) return;
    int e = 0;
    while (e < 3 && prow >= roff[e + 1]) ++e;
    const int j = prow - roff[e];
    const int d4 = threadIdx.x << 2;
    float4 res = make_float4(0.f, 0.f, 0.f, 0.f);
    if (j < cnt3[e]) {
        const int v = idx[e * BT_ + j];
        const int n = v >> 9, b = v & 511;
        const float4 x = *(const float4*)(w + ((long)b << 10) + d4);
        const float4 y = *(const float4*)(a + ((long)b << 10) + d4);
        const float4 z = *(const float4*)(rr + ((long)b << 10) + d4);
        const float4 o0 = *(const float4*)(doff + ((long)(n * 3 + 0) << 10) + d4);
        const float4 o1 = *(const float4*)(doff + ((long)(n * 3 + 1) << 10) + d4);
        const float4 o2 = *(const float4*)(doff + ((long)(n * 3 + 2) << 10) + d4);
        const float c = 1.0f / 3.0f;
        res = make_float4(
            (x.x + y.x + z.x + o0.x + o1.x + o2.x) * c,
            (x.y + y.y + z.y + o0.y + o1.y + o2.y) * c,
            (x.z + y.z + z.z + o0.z + o1.z + o2.z) * c,
            (x.w + y.w + z.w + o0.w + o1.w + o2.w) * c);
    }
    *(float4*)(seq0 + ((long)prow << 10) + d4) = res;
}

// seq[t+1][prow] = mean over 3 chunks of O (f32, stride 3072)
__global__ __launch_bounds__(256) void mean3_bt(
    const float* __restrict__ O, float* __restrict__ dst,
    const int* __restrict__ roff)
{
    const int r = blockIdx.x;
    if (r >= roff[4]) return;
    const int d4 = threadIdx.x << 2;
    const float* p = O + (long)r * 3072 + d4;
    const float4 x = *(const float4*)p;
    const float4 y = *(const float4*)(p + 1024);
    const float4 z = *(const float4*)(p + 2048);
    const float c = 1.0f / 3.0f;
    *(float4*)(dst + ((long)r << 10) + d4) = make_float4(
        (x.x + y.x + z.x) * c, (x.y + y.y + z.y) * c,
        (x.z + y.z + z.z) * c, (x.w + y.w + z.w) * c);
}

// out[n,s,:,b,:] += w[b][e] * O[roff[e]+r, :]   (one expert per launch)
__global__ __launch_bounds__(256) void scatter_bt(
    const float* __restrict__ O, const float* __restrict__ wbuf,
    const int* __restrict__ idx, const int* __restrict__ cnt3,
    const int* __restrict__ roff, float* __restrict__ out, int e, int s)
{
    const int r = blockIdx.x;
    if (r >= cnt3[e]) return;
    const int prow = roff[e] + r;
    const int v = idx[e * BT_ + r];
    const int n = v >> 9, b = v & 511;
    const float wgt = wbuf[b * E_ + e];
    const int d4 = threadIdx.x << 2;
    const float* orow = O + (long)prow * 3072;
    #pragma unroll
    for (int c = 0; c < 3; ++c) {
        const float4 t = *(const float4*)(orow + c * 1024 + d4);
        float* op = out + (((long)((n * STEPS_ + s) * 3 + c) * B_ + b) << 10) + d4;
        float4 o = *(const float4*)op;
        o.x += wgt * t.x; o.y += wgt * t.y; o.z += wgt * t.z; o.w += wgt * t.w;
        *(float4*)op = o;
    }
}

__global__ __launch_bounds__(256) void build_flat_kernel(
    const float* __restrict__ w, const float* __restrict__ a,
    const float* __restrict__ r, float* __restrict__ flat)
{
    const long e4 = ((long)blockIdx.x * 256 + threadIdx.x) << 2;
    const int b = (int)(e4 / 3072);
    const int cd = (int)(e4 % 3072);
    const int c = cd >> 10, d = cd & 1023;
    const float* src = (c == 0) ? w : (c == 1) ? a : r;
    *(float4*)(flat + e4) = *(const float4*)(src + ((long)b << 10) + d);
}

__global__ __launch_bounds__(256) void zero_kernel(float* __restrict__ p, long n4)
{
    const long stride = (long)gridDim.x * 256;
    for (long i = (long)blockIdx.x * 256 + threadIdx.x; i < n4; i += stride)
        *(float4*)(p + i * 4) = make_float4(0.f, 0.f, 0.f, 0.f);
}

// f32 -> bf16 (RNE), vectorized; n4 = count/4
__global__ __launch_bounds__(256) void cvt_bf16_kernel(
    const float* __restrict__ src, unsigned short* __restrict__ dst, long n4)
{
    const long stride = (long)gridDim.x * 256;
    for (long i = (long)blockIdx.x * 256 + threadIdx.x; i < n4; i += stride) {
        const float4 v = *(const float4*)(src + i * 4);
        ushort4 o = make_ushort4(f2bf(v.x), f2bf(v.y), f2bf(v.z), f2bf(v.w));
        *(ushort4*)(dst + i * 4) = o;
    }
}

// =====================================================================
// Host-side GEMM dispatch: per-weight mirror (bf16, pure DMA) or fallback.
// =====================================================================
template<int ACT, int OUTBF>
static inline void G(dim3 grid, hipStream_t s,
                     const unsigned short* A,
                     const float* Wf, const unsigned short* Wm, long wstride, int LDA,
                     const float* bias, long bstride,
                     const float* R, long Rld, void* C, int N, int K,
                     const int* roff, int T)
{
    if (Wm) gemm_bb<ACT, OUTBF><<<grid, 512, 0, s>>>(A, Wm, wstride, LDA, bias, bstride, R, Rld, C, N, K, roff, T);
    else    gemm_wf32<ACT, OUTBF><<<grid, 512, 0, s>>>(A, Wf, wstride, LDA, bias, bstride, R, Rld, C, N, K, roff, T);
}

// =====================================================================
//                          HOST LAUNCH
// =====================================================================

extern "C" void kernel_launch(void* const* d_in, const int* in_sizes, int n_in,
                              void* d_out, int out_size, void* d_ws, size_t ws_size,
                              hipStream_t stream)
{
    const float* iw   = (const float*)d_in[0];
    const float* ia   = (const float*)d_in[1];
    const float* ir   = (const float*)d_in[2];
    const float* doff = (const float*)d_in[3];
    const float* gw1  = (const float*)d_in[4];
    const float* gb1  = (const float*)d_in[5];
    const float* glnw = (const float*)d_in[6];
    const float* glnb = (const float*)d_in[7];
    const float* gw2  = (const float*)d_in[8];
    const float* gb2  = (const float*)d_in[9];
    const float* pos  = (const float*)d_in[10];
    const float* anw  = (const float*)d_in[11];
    const float* anb  = (const float*)d_in[12];
    const float* inw  = (const float*)d_in[13];
    const float* inb  = (const float*)d_in[14];
    const float* oww  = (const float*)d_in[15];
    const float* owb  = (const float*)d_in[16];
    const float* fnw  = (const float*)d_in[17];
    const float* fnb  = (const float*)d_in[18];
    const float* w1   = (const float*)d_in[19];
    const float* b1   = (const float*)d_in[20];
    const float* w2   = (const float*)d_in[21];
    const float* b2   = (const float*)d_in[22];
    const float* tlnw = (const float*)d_in[23];
    const float* tlnb = (const float*)d_in[24];
    const float* tw1  = (const float*)d_in[25];
    const float* tb1  = (const float*)d_in[26];
    const float* tw2  = (const float*)d_in[27];
    const float* tb2  = (const float*)d_in[28];
    float* out = (float*)d_out;

    // ---- workspace layout (floats) — base 79,175,712 ----
    float* ws    = (float*)d_ws;
    float* wbuf  = ws;                               // 2048
    int*   cnt3  = (int*)(wbuf + 2048);              // 16
    int*   roff  = cnt3 + 16;                        // 16
    int*   idxb  = roff + 16;                        // 4*1536 = 6144
    float* flatb = (float*)(idxb + 4 * BT_);         // 512*3072
    float* glin  = flatb + (long)B_ * 3072;          // 512*1024
    float* seq   = glin + (long)B_ * 1024;           // 6*PROWS*1024
    float* st    = seq + 6L * PROWS * 1024;          // TROWS*1024
    unsigned short* xnB  = (unsigned short*)(st + (long)TROWS * 1024);  // TROWS*1024 bf16
    unsigned short* bigB = xnB + (long)TROWS * 1024;                     // TROWS*3072 bf16
    unsigned short* Fbuf = bigB;                               // tri/FFN hidden bf16 (PROWS*2048)
    unsigned short* axB  = xnB;                                // compact attn-out overlaps xnB head
    float* Obuf = (float*)(bigB + 16777216);                   // tri out f32 (PROWS*3072)
    float* stL  = seq + 5L * PROWS * 1024;                     // PROWS*1024 f32 (slab 5 free in-step)
    const size_t BASE = 79175712UL;
    if (ws_size < BASE * sizeof(float)) return;

    // ---- tiered bf16 weight mirrors (greedy, priority by W traffic) ----
    long cap = ((long)(ws_size / 4) - (long)BASE) * 2;   // remaining capacity in ushorts
    unsigned short* mcur = (unsigned short*)(ws + BASE);
    auto take = [&](long n) -> unsigned short* {
        if (cap >= n) { unsigned short* p = mcur; mcur += n; cap -= n; return p; }
        return nullptr;
    };
    unsigned short* w1M  = take((long)E_ * L_ * 4096 * 1024);   // FFN up
    unsigned short* w2M  = take((long)E_ * L_ * 1024 * 4096);   // FFN down
    unsigned short* winM = take((long)E_ * L_ * 3072 * 1024);   // QKV
    unsigned short* t2M  = take((long)E_ * 3072 * 2048);        // tri out
    unsigned short* wowM = take((long)E_ * L_ * 1024 * 1024);   // o-proj
    unsigned short* t1M  = take((long)E_ * 2048 * 1024);        // tri hidden

    // ---- gating (pure f32, bit-stable) ----
    build_flat_kernel<<<B_ * 3, 256, 0, stream>>>(iw, ia, ir, flatb);
    gemm_f32<<<dim3(16, 8), 256, 0, stream>>>(flatb, gw1, gb1, nullptr, glin, B_, 1024, 3072, 0);
    ln_gate<<<B_, 256, 0, stream>>>(glin, glnw, glnb, glin);
    gate_kernel<<<B_ / 4, 256, 0, stream>>>(glin, gw2, gb2, wbuf);
    build_idx2_kernel<<<1, 64, 0, stream>>>(wbuf, idxb, cnt3, roff);

    zero_kernel<<<2048, 256, 0, stream>>>(out, (long)ND_ * STEPS_ * 3 * B_ * 1024 / 4);

    if (w1M)  cvt_bf16_kernel<<<2048, 256, 0, stream>>>(w1,  w1M,  (long)E_ * L_ * 4096 * 1024 / 4);
    if (w2M)  cvt_bf16_kernel<<<2048, 256, 0, stream>>>(w2,  w2M,  (long)E_ * L_ * 1024 * 4096 / 4);
    if (winM) cvt_bf16_kernel<<<2048, 256, 0, stream>>>(inw, winM, (long)E_ * L_ * 3072 * 1024 / 4);
    if (t2M)  cvt_bf16_kernel<<<2048, 256, 0, stream>>>(tw2, t2M,  (long)E_ * 3072 * 2048 / 4);
    if (wowM) cvt_bf16_kernel<<<2048, 256, 0, stream>>>(oww, wowM, (long)E_ * L_ * 1024 * 1024 / 4);
    if (t1M)  cvt_bf16_kernel<<<2048, 256, 0, stream>>>(tw1, t1M,  (long)E_ * 2048 * 1024 / 4);

    seq0_bt<<<PROWS, 256, 0, stream>>>(iw, ia, ir, doff, idxb, cnt3, roff, seq);

    for (int t = 0; t < STEPS_; ++t) {
        const int T = t + 1;
        const int MT = PROWS * T;

        // ===== layer 0 — FULL (all T tokens; layer 1 needs everyone's K/V) =====
        {
            const int l = 0;
            ln_st_bt<<<MT, 256, 0, stream>>>(seq, pos, st,
                                             anw + l * 1024, anb + l * 1024,
                                             (long)L_ * 1024, xnB, roff, T);
            G<0, 1>(dim3(24, MT / 128), stream, xnB,
                    inw + (long)l * 3072 * 1024, winM ? winM + (long)l * 3072 * 1024 : nullptr,
                    (long)L_ * 3072 * 1024, 1024,
                    inb + l * 3072, (long)L_ * 3072, nullptr, 0, bigB, 3072, 1024, roff, T);
            switch (T) {
                case 1: attn_bt<1><<<PROWS * 8 * 1 / 4, 256, 0, stream>>>(bigB, xnB, roff); break;
                case 2: attn_bt<2><<<PROWS * 8 * 2 / 4, 256, 0, stream>>>(bigB, xnB, roff); break;
                case 3: attn_bt<3><<<PROWS * 8 * 3 / 4, 256, 0, stream>>>(bigB, xnB, roff); break;
                case 4: attn_bt<4><<<PROWS * 8 * 4 / 4, 256, 0, stream>>>(bigB, xnB, roff); break;
                case 5: attn_bt<5><<<PROWS * 8 * 5 / 4, 256, 0, stream>>>(bigB, xnB, roff); break;
            }
            G<0, 0>(dim3(8, MT / 128), stream, xnB,
                    oww + (long)l * 1024 * 1024, wowM ? wowM + (long)l * 1024 * 1024 : nullptr,
                    (long)L_ * 1024 * 1024, 1024,
                    owb + l * 1024, (long)L_ * 1024, st, 1024, st, 1024, 1024, roff, T);
            ln_bt<<<MT, 256, 0, stream>>>(st, 1024, fnw + l * 1024, fnb + l * 1024,
                                          (long)L_ * 1024, xnB, roff, T);
            for (int c = 0; c < 2; ++c) {
                G<1, 1>(dim3(16, MT / 128), stream, xnB,
                        w1 + (long)l * 4096 * 1024 + (long)c * 2048 * 1024,
                        w1M ? w1M + (long)l * 4096 * 1024 + (long)c * 2048 * 1024 : nullptr,
                        (long)L_ * 4096 * 1024, 1024,
                        b1 + l * 4096 + c * 2048, (long)L_ * 4096, nullptr, 0, bigB, 2048, 1024, roff, T);
                G<0, 0>(dim3(8, MT / 128), stream, bigB,
                        w2 + (long)l * 1024 * 4096 + (long)c * 2048,
                        w2M ? w2M + (long)l * 1024 * 4096 + (long)c * 2048 : nullptr,
                        (long)L_ * 1024 * 4096, 4096,
                        (c == 0) ? (b2 + l * 1024) : nullptr, (long)L_ * 1024,
                        st, 1024, st, 1024, 2048, roff, T);
            }
        }

        // ===== layer 1 — o-proj/FFN only for the LAST token of each prow =====
        {
            const int l = 1;
            ln_bt<<<MT, 256, 0, stream>>>(st, 1024, anw + l * 1024, anb + l * 1024,
                                          (long)L_ * 1024, xnB, roff, T);
            G<0, 1>(dim3(24, MT / 128), stream, xnB,
                    inw + (long)l * 3072 * 1024, winM ? winM + (long)l * 3072 * 1024 : nullptr,
                    (long)L_ * 3072 * 1024, 1024,
                    inb + l * 3072, (long)L_ * 3072, nullptr, 0, bigB, 3072, 1024, roff, T);
            switch (T) {
                case 1: attn_last<1><<<PROWS * 8 / 4, 256, 0, stream>>>(bigB, axB, roff); break;
                case 2: attn_last<2><<<PROWS * 8 / 4, 256, 0, stream>>>(bigB, axB, roff); break;
                case 3: attn_last<3><<<PROWS * 8 / 4, 256, 0, stream>>>(bigB, axB, roff); break;
                case 4: attn_last<4><<<PROWS * 8 / 4, 256, 0, stream>>>(bigB, axB, roff); break;
                case 5: attn_last<5><<<PROWS * 8 / 4, 256, 0, stream>>>(bigB, axB, roff); break;
            }
            G<0, 0>(dim3(8, PROWS / 128), stream, axB,
                    oww + (long)l * 1024 * 1024, wowM ? wowM + (long)l * 1024 * 1024 : nullptr,
                    (long)L_ * 1024 * 1024, 1024,
                    owb + l * 1024, (long)L_ * 1024,
                    st + (long)t * 1024, (long)T * 1024, stL, 1024, 1024, roff, 1);
            ln_bt<<<PROWS, 256, 0, stream>>>(stL, 1024, fnw + l * 1024, fnb + l * 1024,
                                             (long)L_ * 1024, xnB, roff, 1);
            for (int c = 0; c < 2; ++c) {
                G<1, 1>(dim3(16, PROWS / 128), stream, xnB,
                        w1 + (long)l * 4096 * 1024 + (long)c * 2048 * 1024,
                        w1M ? w1M + (long)l * 4096 * 1024 + (long)c * 2048 * 1024 : nullptr,
                        (long)L_ * 4096 * 1024, 1024,
                        b1 + l * 4096 + c * 2048, (long)L_ * 4096, nullptr, 0, Fbuf, 2048, 1024, roff, 1);
                G<0, 0>(dim3(8, PROWS / 128), stream, Fbuf,
                        w2 + (long)l * 1024 * 4096 + (long)c * 2048,
                        w2M ? w2M + (long)l * 1024 * 4096 + (long)c * 2048 : nullptr,
                        (long)L_ * 1024 * 4096, 4096,
                        (c == 0) ? (b2 + l * 1024) : nullptr, (long)L_ * 1024,
                        stL, 1024, stL, 1024, 2048, roff, 1);
            }
        }

        // triplet projection of last token (stL) -> next seq entry
        ln_bt<<<PROWS, 256, 0, stream>>>(stL, 1024, tlnw, tlnb, 1024, xnB, roff, 1);
        G<1, 1>(dim3(16, PROWS / 128), stream, xnB,
                tw1, t1M, 2048L * 1024, 1024, tb1, 2048, nullptr, 0, Fbuf, 2048, 1024, roff, 1);
        G<0, 0>(dim3(24, PROWS / 128), stream, Fbuf,
                tw2, t2M, 3072L * 2048, 2048, tb2, 3072, nullptr, 0, Obuf, 3072, 2048, roff, 1);
        mean3_bt<<<PROWS, 256, 0, stream>>>(Obuf, seq + (long)(t + 1) * PROWS * 1024, roff);
    }
    // final triplet projection over embs = seq[1..5], one slab at a time
    for (int s = 0; s < STEPS_; ++s) {
        ln_bt<<<PROWS, 256, 0, stream>>>(seq + (long)(s + 1) * PROWS * 1024, 1024,
                                         tlnw, tlnb, 1024, xnB, roff, 1);
        G<1, 1>(dim3(16, PROWS / 128), stream, xnB,
                tw1, t1M, 2048L * 1024, 1024, tb1, 2048, nullptr, 0, Fbuf, 2048, 1024, roff, 1);
        G<0, 0>(dim3(24, PROWS / 128), stream, Fbuf,
                tw2, t2M, 3072L * 2048, 2048, tb2, 3072, nullptr, 0, Obuf, 3072, 2048, roff, 1);
        for (int e = 0; e < E_; ++e)
            scatter_bt<<<BT_, 256, 0, stream>>>(Obuf, wbuf, idxb, cnt3, roff, out, e, s);
    }
}

// Round 15
// 5908.067 us; speedup vs baseline: 1.1738x; 1.0339x over previous
//
#include <hip/hip_runtime.h>
#include <hip/hip_bf16.h>
#include <cstdint>

#define B_  512
#define D_  1024
#define E_  4
#define L_  2
#define FF_ 4096
#define ND_ 3
#define BT_ 1536   // ND_*B_
#define STEPS_ 5
#define H_ 8
#define PROWS 3584         // max sum of pad128(3*cnt_e) over experts
#define TROWS (PROWS * STEPS_)

typedef __attribute__((ext_vector_type(8))) __bf16 bf16x8;
typedef __attribute__((ext_vector_type(8))) unsigned short u16x8;
typedef __attribute__((ext_vector_type(4))) float f32x4;

static __device__ __forceinline__ float gelu_f(float x) {
    return 0.5f * x * (1.0f + erff(x * 0.70710678118654752f));
}

static __device__ __forceinline__ unsigned short f2bf(float x) {
    unsigned u = __builtin_bit_cast(unsigned, x);
    u = (u + 0x7fff + ((u >> 16) & 1)) >> 16;   // RNE
    return (unsigned short)u;
}

static __device__ __forceinline__ float bf2f(unsigned short us) {
    unsigned v = (unsigned)us << 16;
    return __builtin_bit_cast(float, v);
}

static __device__ __forceinline__ void gload16(const void* g, void* l) {
    __builtin_amdgcn_global_load_lds(
        (const __attribute__((address_space(1))) unsigned int*)g,
        (__attribute__((address_space(3))) unsigned int*)l, 16, 0, 0);
}

static __device__ __forceinline__ int pad128(int x) { return (x + 127) & ~127; }

// =====================================================================
// Variant A (fallback): in-kernel W f32->bf16 conversion (round-12 proven).
// =====================================================================
template<int ACT, int OUTBF>
__global__ __launch_bounds__(512) void gemm_wf32(
    const unsigned short* __restrict__ A,
    const float* __restrict__ Wb, long wstride, int LDA,
    const float* __restrict__ biasb, long bstride,
    const float* __restrict__ R, long Rld, void* __restrict__ Cout, int N, int K,
    const int* __restrict__ roff, int T)
{
    const long row0 = (long)blockIdx.y * 128;
    if ((int)row0 >= roff[4] * T) return;
    int e = 0;
    while (e < 3 && (int)row0 >= roff[e + 1] * T) ++e;
    const float* W = Wb + (long)e * wstride;
    const float* bias = biasb ? (biasb + (long)e * bstride) : nullptr;

    __shared__ __align__(16) unsigned short As[2 * 128 * 32];
    __shared__ __align__(16) unsigned short Bs[2 * 128 * 32];
    const int t = threadIdx.x;
    const int lane = t & 63;
    const int wid = t >> 6;
    const int wr = wid >> 1;
    const int wc = wid & 1;
    const long col0 = (long)blockIdx.x * 128;
    const int l15 = lane & 15, l4 = lane >> 4;

    f32x4 acc[2][4] = {};

    const unsigned short* Ag = A + (row0 + (t >> 2)) * (long)K + (t & 3) * 8;
    char* AdBase = (char*)As + t * 16;
    const float* Wg = W + (long)(col0 + (t >> 2)) * LDA + (t & 3) * 8;

    const int K32 = K >> 5;
    float4 w0, w1;

    gload16(Ag, AdBase);
    w0 = *(const float4*)(Wg);
    w1 = *(const float4*)(Wg + 4);
    {
        u16x8 p = {f2bf(w0.x), f2bf(w0.y), f2bf(w0.z), f2bf(w0.w),
                   f2bf(w1.x), f2bf(w1.y), f2bf(w1.z), f2bf(w1.w)};
        *(u16x8*)((char*)Bs + t * 16) = p;
    }
    if (K32 > 1) {
        w0 = *(const float4*)(Wg + 32);
        w1 = *(const float4*)(Wg + 36);
    }
    __syncthreads();

    for (int j = 0; j < K32; ++j) {
        const int cur = j & 1;
        const int nxt = cur ^ 1;
        if (j + 1 < K32) {
            gload16(Ag + ((j + 1) << 5), AdBase + nxt * 8192);
            u16x8 p = {f2bf(w0.x), f2bf(w0.y), f2bf(w0.z), f2bf(w0.w),
                       f2bf(w1.x), f2bf(w1.y), f2bf(w1.z), f2bf(w1.w)};
            *(u16x8*)((char*)Bs + nxt * 8192 + t * 16) = p;
        }
        if (j + 2 < K32) {
            const int k2 = (j + 2) << 5;
            w0 = *(const float4*)(Wg + k2);
            w1 = *(const float4*)(Wg + k2 + 4);
        }
        bf16x8 af[2], bf[4];
        #pragma unroll
        for (int m = 0; m < 2; ++m)
            af[m] = *(const bf16x8*)((const char*)As + cur * 8192 + (wr * 32 + m * 16 + l15) * 64 + l4 * 16);
        #pragma unroll
        for (int n = 0; n < 4; ++n)
            bf[n] = *(const bf16x8*)((const char*)Bs + cur * 8192 + (wc * 64 + n * 16 + l15) * 64 + l4 * 16);
        __builtin_amdgcn_s_setprio(1);
        #pragma unroll
        for (int m = 0; m < 2; ++m)
            #pragma unroll
            for (int n = 0; n < 4; ++n)
                acc[m][n] = __builtin_amdgcn_mfma_f32_16x16x32_bf16(af[m], bf[n], acc[m][n], 0, 0, 0);
        __builtin_amdgcn_s_setprio(0);
        __syncthreads();
    }

    #pragma unroll
    for (int n = 0; n < 4; ++n) {
        const long col = col0 + wc * 64 + n * 16 + l15;
        const float bn = bias ? bias[col] : 0.0f;
        #pragma unroll
        for (int m = 0; m < 2; ++m) {
            const long rbase = row0 + wr * 32 + m * 16 + l4 * 4;
            #pragma unroll
            for (int r = 0; r < 4; ++r) {
                float o = acc[m][n][r] + bn;
                if (ACT) o = gelu_f(o);
                const long coff = (rbase + r) * (long)N + col;
                if (R) o += R[(rbase + r) * Rld + col];
                if (OUTBF) ((unsigned short*)Cout)[coff] = f2bf(o);
                else       ((float*)Cout)[coff] = o;
            }
        }
    }
}

// =====================================================================
// Variant B (mirror): both operands bf16 via pure global_load_lds DMA.
// =====================================================================
template<int ACT, int OUTBF>
__global__ __launch_bounds__(512) void gemm_bb(
    const unsigned short* __restrict__ A,
    const unsigned short* __restrict__ Wb, long wstride, int LDA,
    const float* __restrict__ biasb, long bstride,
    const float* __restrict__ R, long Rld, void* __restrict__ Cout, int N, int K,
    const int* __restrict__ roff, int T)
{
    const long row0 = (long)blockIdx.y * 128;
    if ((int)row0 >= roff[4] * T) return;
    int e = 0;
    while (e < 3 && (int)row0 >= roff[e + 1] * T) ++e;
    const unsigned short* W = Wb + (long)e * wstride;
    const float* bias = biasb ? (biasb + (long)e * bstride) : nullptr;

    __shared__ __align__(16) unsigned short As[2 * 128 * 32];
    __shared__ __align__(16) unsigned short Bs[2 * 128 * 32];
    const int t = threadIdx.x;
    const int lane = t & 63;
    const int wid = t >> 6;
    const int wr = wid >> 1;
    const int wc = wid & 1;
    const long col0 = (long)blockIdx.x * 128;
    const int l15 = lane & 15, l4 = lane >> 4;

    f32x4 acc[2][4] = {};

    const unsigned short* Ag = A + (row0 + (t >> 2)) * (long)K + (t & 3) * 8;
    const unsigned short* Wg = W + (long)(col0 + (t >> 2)) * LDA + (t & 3) * 8;
    char* AdBase = (char*)As + t * 16;
    char* BdBase = (char*)Bs + t * 16;

    const int K32 = K >> 5;

    gload16(Ag, AdBase);
    gload16(Wg, BdBase);
    __syncthreads();

    for (int j = 0; j < K32; ++j) {
        const int cur = j & 1;
        const int nxt = cur ^ 1;
        if (j + 1 < K32) {
            const int k1 = (j + 1) << 5;
            gload16(Ag + k1, AdBase + nxt * 8192);
            gload16(Wg + k1, BdBase + nxt * 8192);
        }
        bf16x8 af[2], bf[4];
        #pragma unroll
        for (int m = 0; m < 2; ++m)
            af[m] = *(const bf16x8*)((const char*)As + cur * 8192 + (wr * 32 + m * 16 + l15) * 64 + l4 * 16);
        #pragma unroll
        for (int n = 0; n < 4; ++n)
            bf[n] = *(const bf16x8*)((const char*)Bs + cur * 8192 + (wc * 64 + n * 16 + l15) * 64 + l4 * 16);
        __builtin_amdgcn_s_setprio(1);
        #pragma unroll
        for (int m = 0; m < 2; ++m)
            #pragma unroll
            for (int n = 0; n < 4; ++n)
                acc[m][n] = __builtin_amdgcn_mfma_f32_16x16x32_bf16(af[m], bf[n], acc[m][n], 0, 0, 0);
        __builtin_amdgcn_s_setprio(0);
        __syncthreads();
    }

    #pragma unroll
    for (int n = 0; n < 4; ++n) {
        const long col = col0 + wc * 64 + n * 16 + l15;
        const float bn = bias ? bias[col] : 0.0f;
        #pragma unroll
        for (int m = 0; m < 2; ++m) {
            const long rbase = row0 + wr * 32 + m * 16 + l4 * 4;
            #pragma unroll
            for (int r = 0; r < 4; ++r) {
                float o = acc[m][n][r] + bn;
                if (ACT) o = gelu_f(o);
                const long coff = (rbase + r) * (long)N + col;
                if (R) o += R[(rbase + r) * Rld + col];
                if (OUTBF) ((unsigned short*)Cout)[coff] = f2bf(o);
                else       ((float*)Cout)[coff] = o;
            }
        }
    }
}

// ---------------- gating GEMM, split-K partials (f32, latency fix) ----------------
// P[kc][512][1024] partial over K chunk [kc*768, kc*768+768)
__global__ __launch_bounds__(256) void gemm_gate_pk(
    const float* __restrict__ A, const float* __restrict__ W,
    float* __restrict__ P)
{
    __shared__ float As[16][68];
    __shared__ float Bs[16][68];
    const int tid = threadIdx.x;
    const int tx = tid & 15;
    const int ty = tid >> 4;
    const long row0 = (long)blockIdx.y * 64;
    const long col0 = (long)blockIdx.x * 64;
    const int kc = blockIdx.z;
    const int lr = tid >> 2;
    const int lq = (tid & 3) << 2;
    const float* Ap = A + (row0 + lr) * 3072L + lq + kc * 768;
    const float* Wp = W + (col0 + lr) * 3072L + lq + kc * 768;
    float acc[4][4] = {};
    for (int k0 = 0; k0 < 768; k0 += 16) {
        const float4 av = *(const float4*)(Ap + k0);
        const float4 wv = *(const float4*)(Wp + k0);
        __syncthreads();
        As[lq + 0][lr] = av.x; As[lq + 1][lr] = av.y;
        As[lq + 2][lr] = av.z; As[lq + 3][lr] = av.w;
        Bs[lq + 0][lr] = wv.x; Bs[lq + 1][lr] = wv.y;
        Bs[lq + 2][lr] = wv.z; Bs[lq + 3][lr] = wv.w;
        __syncthreads();
        #pragma unroll
        for (int kk = 0; kk < 16; ++kk) {
            const float4 a4 = *(const float4*)&As[kk][ty << 2];
            const float4 b4 = *(const float4*)&Bs[kk][tx << 2];
            const float aa[4] = {a4.x, a4.y, a4.z, a4.w};
            const float bb[4] = {b4.x, b4.y, b4.z, b4.w};
            #pragma unroll
            for (int i = 0; i < 4; ++i)
                #pragma unroll
                for (int j = 0; j < 4; ++j)
                    acc[i][j] = fmaf(aa[i], bb[j], acc[i][j]);
        }
    }
    float* Pc = P + (long)kc * 524288;
    #pragma unroll
    for (int i = 0; i < 4; ++i) {
        const long off = (row0 + (ty << 2) + i) * 1024L + col0 + (tx << 2);
        *(float4*)(Pc + off) = make_float4(acc[i][0], acc[i][1], acc[i][2], acc[i][3]);
    }
}

// glin = (((P0+P1)+P2)+P3) + bias
__global__ __launch_bounds__(256) void gate_reduce(
    const float* __restrict__ P, const float* __restrict__ bias,
    float* __restrict__ glin)
{
    const long i4 = ((long)blockIdx.x * 256 + threadIdx.x) << 2;   // < 524288
    const float4 a = *(const float4*)(P + i4);
    const float4 b = *(const float4*)(P + 524288 + i4);
    const float4 c = *(const float4*)(P + 2 * 524288 + i4);
    const float4 d = *(const float4*)(P + 3 * 524288 + i4);
    const float4 bi = *(const float4*)(bias + (i4 & 1023));
    float4 o;
    o.x = ((a.x + b.x) + c.x) + d.x + bi.x;
    o.y = ((a.y + b.y) + c.y) + d.y + bi.y;
    o.z = ((a.z + b.z) + c.z) + d.z + bi.z;
    o.w = ((a.w + b.w) + c.w) + d.w + bi.w;
    *(float4*)(glin + i4) = o;
}

// ---------------- LayerNorm (plain, gating, fused GELU) ----------------
__global__ __launch_bounds__(256) void ln_gate(
    const float* __restrict__ X,
    const float* __restrict__ gamma, const float* __restrict__ beta,
    float* __restrict__ Y)
{
    const long r = blockIdx.x;
    const int tid = threadIdx.x;
    __shared__ float red[8];
    const float4 v = *(const float4*)(X + (r << 10) + (tid << 2));
    float s = v.x + v.y + v.z + v.w;
    #pragma unroll
    for (int off = 32; off; off >>= 1) s += __shfl_xor(s, off);
    if ((tid & 63) == 0) red[tid >> 6] = s;
    __syncthreads();
    const float mean = (red[0] + red[1] + red[2] + red[3]) * (1.0f / 1024.0f);
    const float dx = v.x - mean, dy = v.y - mean, dz = v.z - mean, dw = v.w - mean;
    float s2 = dx * dx + dy * dy + dz * dz + dw * dw;
    #pragma unroll
    for (int off = 32; off; off >>= 1) s2 += __shfl_xor(s2, off);
    if ((tid & 63) == 0) red[4 + (tid >> 6)] = s2;
    __syncthreads();
    const float var = (red[4] + red[5] + red[6] + red[7]) * (1.0f / 1024.0f);
    const float inv = rsqrtf(var + 1e-5f);
    const float4 g = *(const float4*)(gamma + (tid << 2));
    const float4 b = *(const float4*)(beta + (tid << 2));
    float o0 = gelu_f(dx * inv * g.x + b.x);
    float o1 = gelu_f(dy * inv * g.y + b.y);
    float o2 = gelu_f(dz * inv * g.z + b.z);
    float o3 = gelu_f(dw * inv * g.w + b.w);
    *(float4*)(Y + (r << 10) + (tid << 2)) = make_float4(o0, o1, o2, o3);
}

// ---------------- LayerNorm, expert-batched gamma/beta, bf16 out ----------------
__global__ __launch_bounds__(256) void ln_bt(
    const float* __restrict__ X, long xstride,
    const float* __restrict__ gammaB, const float* __restrict__ betaB, long gstride,
    unsigned short* __restrict__ Y, const int* __restrict__ roff, int T)
{
    const long r = blockIdx.x;
    if ((int)r >= roff[4] * T) return;
    int e = 0;
    while (e < 3 && (int)r >= roff[e + 1] * T) ++e;
    const float* gamma = gammaB + (long)e * gstride;
    const float* beta  = betaB  + (long)e * gstride;

    const int tid = threadIdx.x;
    __shared__ float red[8];
    const float4 v = *(const float4*)(X + r * xstride + (tid << 2));
    float s = v.x + v.y + v.z + v.w;
    #pragma unroll
    for (int off = 32; off; off >>= 1) s += __shfl_xor(s, off);
    if ((tid & 63) == 0) red[tid >> 6] = s;
    __syncthreads();
    const float mean = (red[0] + red[1] + red[2] + red[3]) * (1.0f / 1024.0f);
    const float dx = v.x - mean, dy = v.y - mean, dz = v.z - mean, dw = v.w - mean;
    float s2 = dx * dx + dy * dy + dz * dz + dw * dw;
    #pragma unroll
    for (int off = 32; off; off >>= 1) s2 += __shfl_xor(s2, off);
    if ((tid & 63) == 0) red[4 + (tid >> 6)] = s2;
    __syncthreads();
    const float var = (red[4] + red[5] + red[6] + red[7]) * (1.0f / 1024.0f);
    const float inv = rsqrtf(var + 1e-5f);
    const float4 g = *(const float4*)(gamma + (tid << 2));
    const float4 b = *(const float4*)(beta + (tid << 2));
    const float o0 = dx * inv * g.x + b.x;
    const float o1 = dy * inv * g.y + b.y;
    const float o2 = dz * inv * g.z + b.z;
    const float o3 = dw * inv * g.w + b.w;
    ushort4 o = make_ushort4(f2bf(o0), f2bf(o1), f2bf(o2), f2bf(o3));
    *(ushort4*)(Y + (r << 10) + (tid << 2)) = o;
}

// ---------------- FUSED: st = seq+pos; write st; LayerNorm(st) -> bf16 Y ----------------
__global__ __launch_bounds__(256) void ln_st_bt(
    const float* __restrict__ seq, const float* __restrict__ posb,
    float* __restrict__ st,
    const float* __restrict__ gammaB, const float* __restrict__ betaB, long gstride,
    unsigned short* __restrict__ Y, const int* __restrict__ roff, int T)
{
    const int r = blockIdx.x;           // trow in [0, PROWS*T)
    const int prow = r / T;
    if (prow >= roff[4]) return;
    int e = 0;
    while (e < 3 && prow >= roff[e + 1]) ++e;
    const int tau = r - prow * T;
    const float* gamma = gammaB + (long)e * gstride;
    const float* beta  = betaB  + (long)e * gstride;

    const int tid = threadIdx.x;
    const int d4 = tid << 2;
    __shared__ float red[8];
    const float4 sv = *(const float4*)(seq + (((long)tau * PROWS + prow) << 10) + d4);
    const float4 pv = *(const float4*)(posb + (((long)e * 10 + tau) << 10) + d4);
    const float4 v = make_float4(sv.x + pv.x, sv.y + pv.y, sv.z + pv.z, sv.w + pv.w);
    *(float4*)(st + ((long)r << 10) + d4) = v;

    float s = v.x + v.y + v.z + v.w;
    #pragma unroll
    for (int off = 32; off; off >>= 1) s += __shfl_xor(s, off);
    if ((tid & 63) == 0) red[tid >> 6] = s;
    __syncthreads();
    const float mean = (red[0] + red[1] + red[2] + red[3]) * (1.0f / 1024.0f);
    const float dx = v.x - mean, dy = v.y - mean, dz = v.z - mean, dw = v.w - mean;
    float s2 = dx * dx + dy * dy + dz * dz + dw * dw;
    #pragma unroll
    for (int off = 32; off; off >>= 1) s2 += __shfl_xor(s2, off);
    if ((tid & 63) == 0) red[4 + (tid >> 6)] = s2;
    __syncthreads();
    const float var = (red[4] + red[5] + red[6] + red[7]) * (1.0f / 1024.0f);
    const float inv = rsqrtf(var + 1e-5f);
    const float4 g = *(const float4*)(gamma + d4);
    const float4 b = *(const float4*)(beta + d4);
    const float o0 = dx * inv * g.x + b.x;
    const float o1 = dy * inv * g.y + b.y;
    const float o2 = dz * inv * g.z + b.z;
    const float o3 = dw * inv * g.w + b.w;
    ushort4 o = make_ushort4(f2bf(o0), f2bf(o1), f2bf(o2), f2bf(o3));
    *(ushort4*)(Y + ((long)r << 10) + d4) = o;
}

// ---------------- attention (all queries): bf16 qkv in, bf16 out ----------------
template<int TT>
__global__ __launch_bounds__(256) void attn_bt(
    const unsigned short* __restrict__ qkv, unsigned short* __restrict__ o,
    const int* __restrict__ roff)
{
    const int item = (int)(((long)blockIdx.x * 256 + threadIdx.x) >> 6);
    const int lane = threadIdx.x & 63;
    const int tq = item % TT;
    const int h  = (item / TT) & 7;
    const int i  = item / (TT * 8);
    if (i >= roff[4]) return;
    const unsigned short* base = qkv + (long)i * TT * 3072;
    const unsigned short* q = base + (long)tq * 3072 + h * 128;
    const float q0 = bf2f(q[lane]), q1 = bf2f(q[lane + 64]);
    float s[TT];
    const float scale = 0.088388347648318447f;  // 1/sqrt(128)
    #pragma unroll
    for (int tk = 0; tk < TT; ++tk) {
        const unsigned short* k = base + (long)tk * 3072 + 1024 + h * 128;
        float p = q0 * bf2f(k[lane]) + q1 * bf2f(k[lane + 64]);
        #pragma unroll
        for (int off = 32; off; off >>= 1) p += __shfl_xor(p, off);
        s[tk] = p * scale;
    }
    float m = s[0];
    #pragma unroll
    for (int tk = 1; tk < TT; ++tk) m = fmaxf(m, s[tk]);
    float den = 0.f;
    #pragma unroll
    for (int tk = 0; tk < TT; ++tk) { s[tk] = expf(s[tk] - m); den += s[tk]; }
    float o0 = 0.f, o1 = 0.f;
    #pragma unroll
    for (int tk = 0; tk < TT; ++tk) {
        const unsigned short* v = base + (long)tk * 3072 + 2048 + h * 128;
        o0 += s[tk] * bf2f(v[lane]); o1 += s[tk] * bf2f(v[lane + 64]);
    }
    const float id = 1.0f / den;
    unsigned short* op = o + ((long)i * TT + tq) * 1024 + h * 128;
    op[lane] = f2bf(o0 * id); op[lane + 64] = f2bf(o1 * id);
}

// ---------------- attention (LAST query only): compact out (PROWS x 1024) ----------------
template<int TT>
__global__ __launch_bounds__(256) void attn_last(
    const unsigned short* __restrict__ qkv, unsigned short* __restrict__ o,
    const int* __restrict__ roff)
{
    const int item = (int)(((long)blockIdx.x * 256 + threadIdx.x) >> 6);
    const int lane = threadIdx.x & 63;
    const int h  = item & 7;
    const int i  = item >> 3;
    if (i >= roff[4]) return;
    const unsigned short* base = qkv + (long)i * TT * 3072;
    const unsigned short* q = base + (long)(TT - 1) * 3072 + h * 128;
    const float q0 = bf2f(q[lane]), q1 = bf2f(q[lane + 64]);
    float s[TT];
    const float scale = 0.088388347648318447f;
    #pragma unroll
    for (int tk = 0; tk < TT; ++tk) {
        const unsigned short* k = base + (long)tk * 3072 + 1024 + h * 128;
        float p = q0 * bf2f(k[lane]) + q1 * bf2f(k[lane + 64]);
        #pragma unroll
        for (int off = 32; off; off >>= 1) p += __shfl_xor(p, off);
        s[tk] = p * scale;
    }
    float m = s[0];
    #pragma unroll
    for (int tk = 1; tk < TT; ++tk) m = fmaxf(m, s[tk]);
    float den = 0.f;
    #pragma unroll
    for (int tk = 0; tk < TT; ++tk) { s[tk] = expf(s[tk] - m); den += s[tk]; }
    float o0 = 0.f, o1 = 0.f;
    #pragma unroll
    for (int tk = 0; tk < TT; ++tk) {
        const unsigned short* v = base + (long)tk * 3072 + 2048 + h * 128;
        o0 += s[tk] * bf2f(v[lane]); o1 += s[tk] * bf2f(v[lane + 64]);
    }
    const float id = 1.0f / den;
    unsigned short* op = o + (long)i * 1024 + h * 128;
    op[lane] = f2bf(o0 * id); op[lane + 64] = f2bf(o1 * id);
}

// ---------------- gating ----------------
__global__ __launch_bounds__(256) void gate_kernel(
    const float* __restrict__ g, const float* __restrict__ gw2,
    const float* __restrict__ gb2, float* __restrict__ wout)
{
    const int b = (int)(((long)blockIdx.x * 256 + threadIdx.x) >> 6);
    const int lane = threadIdx.x & 63;
    float acc[E_] = {};
    const float* row = g + (long)b * 1024;
    for (int d = lane; d < 1024; d += 64) {
        const float x = row[d];
        #pragma unroll
        for (int j = 0; j < E_; ++j) acc[j] += x * gw2[j * 1024 + d];
    }
    #pragma unroll
    for (int j = 0; j < E_; ++j) {
        #pragma unroll
        for (int off = 32; off; off >>= 1) acc[j] += __shfl_xor(acc[j], off);
        acc[j] += gb2[j];
    }
    int i0 = 0; float v0 = acc[0];
    #pragma unroll
    for (int j = 1; j < E_; ++j) if (acc[j] > v0) { v0 = acc[j]; i0 = j; }
    int i1 = -1; float v1 = -1e30f;
    #pragma unroll
    for (int j = 0; j < E_; ++j) if (j != i0 && acc[j] > v1) { v1 = acc[j]; i1 = j; }
    const float p1 = expf(v1 - v0);
    const float den = 1.0f + p1;
    const float g0 = 1.0f / den, g1 = p1 / den;
    if (lane < E_) wout[b * E_ + lane] = (lane == i0) ? g0 : (lane == i1) ? g1 : 0.0f;
}

// single block: per-expert compact lists + packed-row offsets + rank3 table
__global__ __launch_bounds__(64) void build_idx2_kernel(
    const float* __restrict__ wbuf, int* __restrict__ idx,
    int* __restrict__ cnt3, int* __restrict__ roff, int* __restrict__ rank3)
{
    const int lane = threadIdx.x;
    int pads[E_];
    for (int e = 0; e < E_; ++e) {
        int* my = idx + e * BT_;
        int base = 0;
        for (int chunk = 0; chunk < 8; ++chunk) {
            const int b = chunk * 64 + lane;
            const bool sel = wbuf[b * E_ + e] > 0.0f;
            const unsigned long long mask = __ballot(sel);
            const int pos = base + (int)__popcll(mask & ((1ull << lane) - 1ull));
            if (sel) {
                my[3 * pos + 0] = b;
                my[3 * pos + 1] = 512 + b;
                my[3 * pos + 2] = 1024 + b;
                rank3[(e << 9) + b] = 3 * pos;
            }
            base += (int)__popcll(mask);
        }
        if (lane == 0) cnt3[e] = 3 * base;
        pads[e] = pad128(3 * base);
    }
    if (lane == 0) {
        roff[0] = 0;
        for (int e = 0; e < E_; ++e) roff[e + 1] = roff[e] + pads[e];
    }
}

// packed seq0: prow -> (e, j); gather or zero
__global__ __launch_bounds__(256) void seq0_bt(
    const float* __restrict__ w, const float* __restrict__ a,
    const float* __restrict__ rr, const float* __restrict__ doff,
    const int* __restrict__ idx, const int* __restrict__ cnt3,
    const int* __restrict__ roff, float* __restrict__ seq0)
{
    const int prow = blockIdx.x;
    if (prow >= roff[4]) return;
    int e = 0;
    while (e < 3 && prow >= roff[e + 1]) ++e;
    const int j = prow - roff[e];
    const int d4 = threadIdx.x << 2;
    float4 res = make_float4(0.f, 0.f, 0.f, 0.f);
    if (j < cnt3[e]) {
        const int v = idx[e * BT_ + j];
        const int n = v >> 9, b = v & 511;
        const float4 x = *(const float4*)(w + ((long)b << 10) + d4);
        const float4 y = *(const float4*)(a + ((long)b << 10) + d4);
        const float4 z = *(const float4*)(rr + ((long)b << 10) + d4);
        const float4 o0 = *(const float4*)(doff + ((long)(n * 3 + 0) << 10) + d4);
        const float4 o1 = *(const float4*)(doff + ((long)(n * 3 + 1) << 10) + d4);
        const float4 o2 = *(const float4*)(doff + ((long)(n * 3 + 2) << 10) + d4);
        const float c = 1.0f / 3.0f;
        res = make_float4(
            (x.x + y.x + z.x + o0.x + o1.x + o2.x) * c,
            (x.y + y.y + z.y + o0.y + o1.y + o2.y) * c,
            (x.z + y.z + z.z + o0.z + o1.z + o2.z) * c,
            (x.w + y.w + z.w + o0.w + o1.w + o2.w) * c);
    }
    *(float4*)(seq0 + ((long)prow << 10) + d4) = res;
}

// seq[t+1][prow] = mean over 3 chunks of O (f32, stride 3072)
__global__ __launch_bounds__(256) void mean3_bt(
    const float* __restrict__ O, float* __restrict__ dst,
    const int* __restrict__ roff)
{
    const int r = blockIdx.x;
    if (r >= roff[4]) return;
    const int d4 = threadIdx.x << 2;
    const float* p = O + (long)r * 3072 + d4;
    const float4 x = *(const float4*)p;
    const float4 y = *(const float4*)(p + 1024);
    const float4 z = *(const float4*)(p + 2048);
    const float c = 1.0f / 3.0f;
    *(float4*)(dst + ((long)r << 10) + d4) = make_float4(
        (x.x + y.x + z.x) * c, (x.y + y.y + z.y) * c,
        (x.z + y.z + z.z) * c, (x.w + y.w + z.w) * c);
}

// Fused write-only combine: out[n,s,:,b,:] = sum_{e sel(b)} w[b][e]*O[prow(e,n,b),:]
// One block per (n*512+b). Ascending-e accumulation matches old scatter order.
__global__ __launch_bounds__(256) void combine_bt(
    const float* __restrict__ O, const float* __restrict__ wbuf,
    const int* __restrict__ rank3, const int* __restrict__ roff,
    float* __restrict__ out, int s)
{
    const int r = blockIdx.x;           // n*512 + b
    const int n = r >> 9, b = r & 511;
    const int d4 = threadIdx.x << 2;
    float4 acc[3];
    #pragma unroll
    for (int c = 0; c < 3; ++c) acc[c] = make_float4(0.f, 0.f, 0.f, 0.f);
    #pragma unroll
    for (int e = 0; e < E_; ++e) {
        const float w = wbuf[b * E_ + e];
        if (w > 0.f) {
            const int prow = roff[e] + rank3[(e << 9) + b] + n;
            const float* row = O + (long)prow * 3072 + d4;
            #pragma unroll
            for (int c = 0; c < 3; ++c) {
                const float4 t = *(const float4*)(row + c * 1024);
                acc[c].x += w * t.x; acc[c].y += w * t.y;
                acc[c].z += w * t.z; acc[c].w += w * t.w;
            }
        }
    }
    #pragma unroll
    for (int c = 0; c < 3; ++c) {
        float* op = out + (((long)((n * STEPS_ + s) * 3 + c) * B_ + b) << 10) + d4;
        *(float4*)op = acc[c];
    }
}

__global__ __launch_bounds__(256) void build_flat_kernel(
    const float* __restrict__ w, const float* __restrict__ a,
    const float* __restrict__ r, float* __restrict__ flat)
{
    const long e4 = ((long)blockIdx.x * 256 + threadIdx.x) << 2;
    const int b = (int)(e4 / 3072);
    const int cd = (int)(e4 % 3072);
    const int c = cd >> 10, d = cd & 1023;
    const float* src = (c == 0) ? w : (c == 1) ? a : r;
    *(float4*)(flat + e4) = *(const float4*)(src + ((long)b << 10) + d);
}

// f32 -> bf16 (RNE), vectorized; n4 = count/4
__global__ __launch_bounds__(256) void cvt_bf16_kernel(
    const float* __restrict__ src, unsigned short* __restrict__ dst, long n4)
{
    const long stride = (long)gridDim.x * 256;
    for (long i = (long)blockIdx.x * 256 + threadIdx.x; i < n4; i += stride) {
        const float4 v = *(const float4*)(src + i * 4);
        ushort4 o = make_ushort4(f2bf(v.x), f2bf(v.y), f2bf(v.z), f2bf(v.w));
        *(ushort4*)(dst + i * 4) = o;
    }
}

// =====================================================================
// Host-side GEMM dispatch: per-weight mirror (bf16, pure DMA) or fallback.
// =====================================================================
template<int ACT, int OUTBF>
static inline void G(dim3 grid, hipStream_t s,
                     const unsigned short* A,
                     const float* Wf, const unsigned short* Wm, long wstride, int LDA,
                     const float* bias, long bstride,
                     const float* R, long Rld, void* C, int N, int K,
                     const int* roff, int T)
{
    if (Wm) gemm_bb<ACT, OUTBF><<<grid, 512, 0, s>>>(A, Wm, wstride, LDA, bias, bstride, R, Rld, C, N, K, roff, T);
    else    gemm_wf32<ACT, OUTBF><<<grid, 512, 0, s>>>(A, Wf, wstride, LDA, bias, bstride, R, Rld, C, N, K, roff, T);
}

// =====================================================================
//                          HOST LAUNCH
// =====================================================================

extern "C" void kernel_launch(void* const* d_in, const int* in_sizes, int n_in,
                              void* d_out, int out_size, void* d_ws, size_t ws_size,
                              hipStream_t stream)
{
    const float* iw   = (const float*)d_in[0];
    const float* ia   = (const float*)d_in[1];
    const float* ir   = (const float*)d_in[2];
    const float* doff = (const float*)d_in[3];
    const float* gw1  = (const float*)d_in[4];
    const float* gb1  = (const float*)d_in[5];
    const float* glnw = (const float*)d_in[6];
    const float* glnb = (const float*)d_in[7];
    const float* gw2  = (const float*)d_in[8];
    const float* gb2  = (const float*)d_in[9];
    const float* pos  = (const float*)d_in[10];
    const float* anw  = (const float*)d_in[11];
    const float* anb  = (const float*)d_in[12];
    const float* inw  = (const float*)d_in[13];
    const float* inb  = (const float*)d_in[14];
    const float* oww  = (const float*)d_in[15];
    const float* owb  = (const float*)d_in[16];
    const float* fnw  = (const float*)d_in[17];
    const float* fnb  = (const float*)d_in[18];
    const float* w1   = (const float*)d_in[19];
    const float* b1   = (const float*)d_in[20];
    const float* w2   = (const float*)d_in[21];
    const float* b2   = (const float*)d_in[22];
    const float* tlnw = (const float*)d_in[23];
    const float* tlnb = (const float*)d_in[24];
    const float* tw1  = (const float*)d_in[25];
    const float* tb1  = (const float*)d_in[26];
    const float* tw2  = (const float*)d_in[27];
    const float* tb2  = (const float*)d_in[28];
    float* out = (float*)d_out;

    // ---- workspace layout (floats) — base 79,177,760 ----
    float* ws    = (float*)d_ws;
    float* wbuf  = ws;                               // 2048
    int*   cnt3  = (int*)(wbuf + 2048);              // 16
    int*   roff  = cnt3 + 16;                        // 16
    int*   idxb  = roff + 16;                        // 4*1536 = 6144
    int*   rank3 = idxb + 4 * BT_;                   // 4*512 = 2048
    float* flatb = (float*)(rank3 + 2048);           // 512*3072
    float* glin  = flatb + (long)B_ * 3072;          // 512*1024
    float* seq   = glin + (long)B_ * 1024;           // 6*PROWS*1024
    float* st    = seq + 6L * PROWS * 1024;          // TROWS*1024 (also gating scratch)
    unsigned short* xnB  = (unsigned short*)(st + (long)TROWS * 1024);  // TROWS*1024 bf16
    unsigned short* bigB = xnB + (long)TROWS * 1024;                     // TROWS*3072 bf16
    unsigned short* Fbuf = bigB;                               // tri/FFN hidden bf16 (PROWS*2048)
    unsigned short* axB  = xnB;                                // compact attn-out overlaps xnB head
    float* Obuf = (float*)(bigB + 16777216);                   // tri out f32 (PROWS*3072)
    float* stL  = seq + 5L * PROWS * 1024;                     // PROWS*1024 f32 (slab 5 free in-step)
    const size_t BASE = 79177760UL;
    if (ws_size < BASE * sizeof(float)) return;

    // ---- tiered bf16 weight mirrors (greedy, priority by W traffic) ----
    long cap = ((long)(ws_size / 4) - (long)BASE) * 2;   // remaining capacity in ushorts
    unsigned short* mcur = (unsigned short*)(ws + BASE);
    auto take = [&](long n) -> unsigned short* {
        if (cap >= n) { unsigned short* p = mcur; mcur += n; cap -= n; return p; }
        return nullptr;
    };
    unsigned short* w1M  = take((long)E_ * L_ * 4096 * 1024);   // FFN up
    unsigned short* w2M  = take((long)E_ * L_ * 1024 * 4096);   // FFN down
    unsigned short* winM = take((long)E_ * L_ * 3072 * 1024);   // QKV
    unsigned short* t2M  = take((long)E_ * 3072 * 2048);        // tri out
    unsigned short* wowM = take((long)E_ * L_ * 1024 * 1024);   // o-proj
    unsigned short* t1M  = take((long)E_ * 2048 * 1024);        // tri hidden

    // ---- gating (f32, split-K=4 for parallelism; scratch = st) ----
    build_flat_kernel<<<B_ * 3, 256, 0, stream>>>(iw, ia, ir, flatb);
    gemm_gate_pk<<<dim3(16, 8, 4), 256, 0, stream>>>(flatb, gw1, st);
    gate_reduce<<<512, 256, 0, stream>>>(st, gb1, glin);
    ln_gate<<<B_, 256, 0, stream>>>(glin, glnw, glnb, glin);
    gate_kernel<<<B_ / 4, 256, 0, stream>>>(glin, gw2, gb2, wbuf);
    build_idx2_kernel<<<1, 64, 0, stream>>>(wbuf, idxb, cnt3, roff, rank3);

    if (w1M)  cvt_bf16_kernel<<<2048, 256, 0, stream>>>(w1,  w1M,  (long)E_ * L_ * 4096 * 1024 / 4);
    if (w2M)  cvt_bf16_kernel<<<2048, 256, 0, stream>>>(w2,  w2M,  (long)E_ * L_ * 1024 * 4096 / 4);
    if (winM) cvt_bf16_kernel<<<2048, 256, 0, stream>>>(inw, winM, (long)E_ * L_ * 3072 * 1024 / 4);
    if (t2M)  cvt_bf16_kernel<<<2048, 256, 0, stream>>>(tw2, t2M,  (long)E_ * 3072 * 2048 / 4);
    if (wowM) cvt_bf16_kernel<<<2048, 256, 0, stream>>>(oww, wowM, (long)E_ * L_ * 1024 * 1024 / 4);
    if (t1M)  cvt_bf16_kernel<<<2048, 256, 0, stream>>>(tw1, t1M,  (long)E_ * 2048 * 1024 / 4);

    seq0_bt<<<PROWS, 256, 0, stream>>>(iw, ia, ir, doff, idxb, cnt3, roff, seq);

    for (int t = 0; t < STEPS_; ++t) {
        const int T = t + 1;
        const int MT = PROWS * T;

        // ===== layer 0 — FULL (all T tokens; layer 1 needs everyone's K/V) =====
        {
            const int l = 0;
            ln_st_bt<<<MT, 256, 0, stream>>>(seq, pos, st,
                                             anw + l * 1024, anb + l * 1024,
                                             (long)L_ * 1024, xnB, roff, T);
            G<0, 1>(dim3(24, MT / 128), stream, xnB,
                    inw + (long)l * 3072 * 1024, winM ? winM + (long)l * 3072 * 1024 : nullptr,
                    (long)L_ * 3072 * 1024, 1024,
                    inb + l * 3072, (long)L_ * 3072, nullptr, 0, bigB, 3072, 1024, roff, T);
            switch (T) {
                case 1: attn_bt<1><<<PROWS * 8 * 1 / 4, 256, 0, stream>>>(bigB, xnB, roff); break;
                case 2: attn_bt<2><<<PROWS * 8 * 2 / 4, 256, 0, stream>>>(bigB, xnB, roff); break;
                case 3: attn_bt<3><<<PROWS * 8 * 3 / 4, 256, 0, stream>>>(bigB, xnB, roff); break;
                case 4: attn_bt<4><<<PROWS * 8 * 4 / 4, 256, 0, stream>>>(bigB, xnB, roff); break;
                case 5: attn_bt<5><<<PROWS * 8 * 5 / 4, 256, 0, stream>>>(bigB, xnB, roff); break;
            }
            G<0, 0>(dim3(8, MT / 128), stream, xnB,
                    oww + (long)l * 1024 * 1024, wowM ? wowM + (long)l * 1024 * 1024 : nullptr,
                    (long)L_ * 1024 * 1024, 1024,
                    owb + l * 1024, (long)L_ * 1024, st, 1024, st, 1024, 1024, roff, T);
            ln_bt<<<MT, 256, 0, stream>>>(st, 1024, fnw + l * 1024, fnb + l * 1024,
                                          (long)L_ * 1024, xnB, roff, T);
            for (int c = 0; c < 2; ++c) {
                G<1, 1>(dim3(16, MT / 128), stream, xnB,
                        w1 + (long)l * 4096 * 1024 + (long)c * 2048 * 1024,
                        w1M ? w1M + (long)l * 4096 * 1024 + (long)c * 2048 * 1024 : nullptr,
                        (long)L_ * 4096 * 1024, 1024,
                        b1 + l * 4096 + c * 2048, (long)L_ * 4096, nullptr, 0, bigB, 2048, 1024, roff, T);
                G<0, 0>(dim3(8, MT / 128), stream, bigB,
                        w2 + (long)l * 1024 * 4096 + (long)c * 2048,
                        w2M ? w2M + (long)l * 1024 * 4096 + (long)c * 2048 : nullptr,
                        (long)L_ * 1024 * 4096, 4096,
                        (c == 0) ? (b2 + l * 1024) : nullptr, (long)L_ * 1024,
                        st, 1024, st, 1024, 2048, roff, T);
            }
        }

        // ===== layer 1 — o-proj/FFN only for the LAST token of each prow =====
        {
            const int l = 1;
            ln_bt<<<MT, 256, 0, stream>>>(st, 1024, anw + l * 1024, anb + l * 1024,
                                          (long)L_ * 1024, xnB, roff, T);
            G<0, 1>(dim3(24, MT / 128), stream, xnB,
                    inw + (long)l * 3072 * 1024, winM ? winM + (long)l * 3072 * 1024 : nullptr,
                    (long)L_ * 3072 * 1024, 1024,
                    inb + l * 3072, (long)L_ * 3072, nullptr, 0, bigB, 3072, 1024, roff, T);
            switch (T) {
                case 1: attn_last<1><<<PROWS * 8 / 4, 256, 0, stream>>>(bigB, axB, roff); break;
                case 2: attn_last<2><<<PROWS * 8 / 4, 256, 0, stream>>>(bigB, axB, roff); break;
                case 3: attn_last<3><<<PROWS * 8 / 4, 256, 0, stream>>>(bigB, axB, roff); break;
                case 4: attn_last<4><<<PROWS * 8 / 4, 256, 0, stream>>>(bigB, axB, roff); break;
                case 5: attn_last<5><<<PROWS * 8 / 4, 256, 0, stream>>>(bigB, axB, roff); break;
            }
            G<0, 0>(dim3(8, PROWS / 128), stream, axB,
                    oww + (long)l * 1024 * 1024, wowM ? wowM + (long)l * 1024 * 1024 : nullptr,
                    (long)L_ * 1024 * 1024, 1024,
                    owb + l * 1024, (long)L_ * 1024,
                    st + (long)t * 1024, (long)T * 1024, stL, 1024, 1024, roff, 1);
            ln_bt<<<PROWS, 256, 0, stream>>>(stL, 1024, fnw + l * 1024, fnb + l * 1024,
                                             (long)L_ * 1024, xnB, roff, 1);
            for (int c = 0; c < 2; ++c) {
                G<1, 1>(dim3(16, PROWS / 128), stream, xnB,
                        w1 + (long)l * 4096 * 1024 + (long)c * 2048 * 1024,
                        w1M ? w1M + (long)l * 4096 * 1024 + (long)c * 2048 * 1024 : nullptr,
                        (long)L_ * 4096 * 1024, 1024,
                        b1 + l * 4096 + c * 2048, (long)L_ * 4096, nullptr, 0, Fbuf, 2048, 1024, roff, 1);
                G<0, 0>(dim3(8, PROWS / 128), stream, Fbuf,
                        w2 + (long)l * 1024 * 4096 + (long)c * 2048,
                        w2M ? w2M + (long)l * 1024 * 4096 + (long)c * 2048 : nullptr,
                        (long)L_ * 1024 * 4096, 4096,
                        (c == 0) ? (b2 + l * 1024) : nullptr, (long)L_ * 1024,
                        stL, 1024, stL, 1024, 2048, roff, 1);
            }
        }

        // triplet projection of last token (stL) -> next seq entry
        ln_bt<<<PROWS, 256, 0, stream>>>(stL, 1024, tlnw, tlnb, 1024, xnB, roff, 1);
        G<1, 1>(dim3(16, PROWS / 128), stream, xnB,
                tw1, t1M, 2048L * 1024, 1024, tb1, 2048, nullptr, 0, Fbuf, 2048, 1024, roff, 1);
        G<0, 0>(dim3(24, PROWS / 128), stream, Fbuf,
                tw2, t2M, 3072L * 2048, 2048, tb2, 3072, nullptr, 0, Obuf, 3072, 2048, roff, 1);
        mean3_bt<<<PROWS, 256, 0, stream>>>(Obuf, seq + (long)(t + 1) * PROWS * 1024, roff);
    }
    // final triplet projection over embs = seq[1..5]; fused write-only combine
    for (int s = 0; s < STEPS_; ++s) {
        ln_bt<<<PROWS, 256, 0, stream>>>(seq + (long)(s + 1) * PROWS * 1024, 1024,
                                         tlnw, tlnb, 1024, xnB, roff, 1);
        G<1, 1>(dim3(16, PROWS / 128), stream, xnB,
                tw1, t1M, 2048L * 1024, 1024, tb1, 2048, nullptr, 0, Fbuf, 2048, 1024, roff, 1);
        G<0, 0>(dim3(24, PROWS / 128), stream, Fbuf,
                tw2, t2M, 3072L * 2048, 2048, tb2, 3072, nullptr, 0, Obuf, 3072, 2048, roff, 1);
        combine_bt<<<BT_, 256, 0, stream>>>(Obuf, wbuf, rank3, roff, out, s);
    }
}